// Round 14
// baseline (182.116 us; speedup 1.0000x reference)
//
#include <hip/hip_runtime.h>
#include <hip/hip_bf16.h>
#include <math.h>

#define B_  4
#define S_  4096
#define D_  1024
#define KD_ 128
#define NSPL 4            // KV splits
#define NIT  (S_ / NSPL / 32)  // 32 iterations of KBLK=32

typedef __attribute__((ext_vector_type(8))) short short8;
typedef __attribute__((ext_vector_type(4))) float f32x4;
typedef __attribute__((ext_vector_type(16))) float f32x16;
typedef __attribute__((ext_vector_type(4))) unsigned short us4;
typedef __attribute__((ext_vector_type(4))) unsigned int u32x4;

__device__ __forceinline__ unsigned short f2bf(float f) {
    __hip_bfloat16 h = __float2bfloat16(f);
    return *reinterpret_cast<unsigned short*>(&h);
}

__device__ __forceinline__ f32x4 mfma_bf16(short8 a, short8 b, f32x4 c) {
    return __builtin_amdgcn_mfma_f32_16x16x32_bf16(a, b, c, 0, 0, 0);
}

__device__ __forceinline__ f32x16 mfma32_bf16(short8 a, short8 b, f32x16 c) {
    return __builtin_amdgcn_mfma_f32_32x32x16_bf16(a, b, c, 0, 0, 0);
}

__device__ __forceinline__ unsigned int cvt_pk_bf16(float lo, float hi_) {
    unsigned int r;
    asm("v_cvt_pk_bf16_f32 %0, %1, %2" : "=v"(r) : "v"(lo), "v"(hi_));
    return r;
}

__device__ __forceinline__ void g2l16(const void* g, void* l) {
    __builtin_amdgcn_global_load_lds(
        (const __attribute__((address_space(1))) unsigned int*)g,
        (__attribute__((address_space(3))) unsigned int*)l, 16, 0, 0);
}

// ---------------------------------------------------------------------------
// Convert weights [D,128] fp32 -> Wt [3][128][D] bf16 (transposed).
// Q weight folds in log2(e)/sqrt(128) so softmax can use native exp2.
__global__ void convert_w_kernel(const float* __restrict__ wq,
                                 const float* __restrict__ wk,
                                 const float* __restrict__ wv,
                                 unsigned short* __restrict__ wt) {
    int t = blockIdx.x * 256 + threadIdx.x;       // 0..49151
    int w = t >> 14;
    int r = t & 16383;
    int n = r & 127;
    int k8 = r >> 7;                               // 0..127
    const float* src = (w == 0) ? wq : (w == 1) ? wk : wv;
    float scale = (w == 0) ? 0.12751725551033443f : 1.0f;  // log2e/sqrt(128)
    short8 v;
#pragma unroll
    for (int i = 0; i < 8; ++i)
        v[i] = (short)f2bf(src[(size_t)(k8 * 8 + i) * KD_ + n] * scale);
    *reinterpret_cast<short8*>(&wt[(size_t)w * KD_ * D_ + (size_t)n * D_ + k8 * 8]) = v;
}

// ---------------------------------------------------------------------------
// Projection GEMM: C[16384,128] = X[16384,1024] @ W.  NT form, Wt[128][1024].
// 1-D grid of 384; bid = (m&7) + 8*which + 24*(m>>3) so the 3 which-blocks of
// one mtile land on the SAME XCD -> X tile read once from HBM, L2-hit twice.
__global__ __launch_bounds__(256) void proj_kernel(
        const float* __restrict__ X, const unsigned short* __restrict__ Wt,
        unsigned short* __restrict__ Qo, unsigned short* __restrict__ Ko,
        unsigned short* __restrict__ Vt) {
    const int bid = blockIdx.x;
    const int g = bid / 24;
    const int local = bid - g * 24;
    const int which = local >> 3;
    const int mtile = g * 8 + (local & 7);
    const int m0 = mtile * 128;
    const int tid = threadIdx.x;
    const int lane = tid & 63;
    const int wid = tid >> 6;
    const int wr = wid >> 1, wc = wid & 1;
    const int l15 = lane & 15, l4 = lane >> 4;

    __shared__ __align__(16) unsigned short Asm[128 * 64];
    __shared__ __align__(16) unsigned short Bsm[128 * 64];
    __shared__ __align__(16) unsigned short Tsm[128 * 128];

    const unsigned short* W = Wt + (size_t)which * KD_ * D_;

    f32x4 acc[4][4];
#pragma unroll
    for (int r = 0; r < 4; ++r)
#pragma unroll
        for (int c = 0; c < 4; ++c) acc[r][c] = (f32x4)0.0f;

    for (int k0 = 0; k0 < D_; k0 += 64) {
#pragma unroll
        for (int i = 0; i < 8; ++i) {
            int f = tid + i * 256;
            int row = f >> 4, c4 = f & 15;
            float4 xv = *reinterpret_cast<const float4*>(
                &X[(size_t)(m0 + row) * D_ + k0 + c4 * 4]);
            us4 h;
            h.x = f2bf(xv.x); h.y = f2bf(xv.y); h.z = f2bf(xv.z); h.w = f2bf(xv.w);
            *reinterpret_cast<us4*>(&Asm[row * 64 + c4 * 4]) = h;
        }
#pragma unroll
        for (int i = 0; i < 4; ++i) {
            int gg = tid + i * 256;
            int n = gg >> 3, c8 = gg & 7;
            *reinterpret_cast<short8*>(&Bsm[n * 64 + c8 * 8]) =
                *reinterpret_cast<const short8*>(&W[(size_t)n * D_ + k0 + c8 * 8]);
        }
        __syncthreads();

        short8 a[4][2], b[4][2];
#pragma unroll
        for (int rt = 0; rt < 4; ++rt)
#pragma unroll
            for (int kc = 0; kc < 2; ++kc)
                a[rt][kc] = *reinterpret_cast<const short8*>(
                    &Asm[(wr * 64 + rt * 16 + l15) * 64 + kc * 32 + l4 * 8]);
#pragma unroll
        for (int ct = 0; ct < 4; ++ct)
#pragma unroll
            for (int kc = 0; kc < 2; ++kc)
                b[ct][kc] = *reinterpret_cast<const short8*>(
                    &Bsm[(wc * 64 + ct * 16 + l15) * 64 + kc * 32 + l4 * 8]);
#pragma unroll
        for (int kc = 0; kc < 2; ++kc)
#pragma unroll
            for (int rt = 0; rt < 4; ++rt)
#pragma unroll
                for (int ct = 0; ct < 4; ++ct)
                    acc[rt][ct] = mfma_bf16(a[rt][kc], b[ct][kc], acc[rt][ct]);
        __syncthreads();
    }

    if (which < 2) {
        unsigned short* O = (which == 0) ? Qo : Ko;
#pragma unroll
        for (int rt = 0; rt < 4; ++rt)
#pragma unroll
            for (int ct = 0; ct < 4; ++ct)
#pragma unroll
                for (int j = 0; j < 4; ++j) {
                    int row = m0 + wr * 64 + rt * 16 + l4 * 4 + j;
                    int col = wc * 64 + ct * 16 + l15;
                    O[(size_t)row * KD_ + col] = f2bf(acc[rt][ct][j]);
                }
    } else {
#pragma unroll
        for (int rt = 0; rt < 4; ++rt)
#pragma unroll
            for (int ct = 0; ct < 4; ++ct)
#pragma unroll
                for (int j = 0; j < 4; ++j) {
                    int row = wr * 64 + rt * 16 + l4 * 4 + j;  // s-local
                    int col = wc * 64 + ct * 16 + l15;          // n
                    Tsm[col * 128 + row] = f2bf(acc[rt][ct][j]);
                }
        __syncthreads();
        int bb = m0 >> 12;
        int s0 = m0 & 4095;
#pragma unroll
        for (int i = 0; i < 8; ++i) {
            int gg = tid + i * 256;
            int n = gg >> 4, s8 = gg & 15;
            *reinterpret_cast<short8*>(
                &Vt[(size_t)bb * KD_ * S_ + (size_t)n * S_ + s0 + s8 * 8]) =
                *reinterpret_cast<short8*>(&Tsm[n * 128 + s8 * 8]);
        }
    }
}

// ---------------------------------------------------------------------------
// R14 flash attention, split-KV x4, 4-deep ring + counted vmcnt (R13), with
// (a) 4-bit K swizzle (4-way -> 2-way bank conflicts on K ds_read_b128) and
// (b) FUSED MERGE: last split-block per tile (device-scope atomic counter)
// re-reads the 4 bf16 partials and writes Out — no separate merge kernel.
__global__ __launch_bounds__(256, 2) void attn_split_kernel(
        const unsigned short* __restrict__ Q,
        const unsigned short* __restrict__ Kb,
        const unsigned short* __restrict__ Vt,
        unsigned short* __restrict__ part16, float* __restrict__ lsumP,
        int* __restrict__ cnt, float* __restrict__ Out) {
    const int bid = blockIdx.x;       // 0..511
    const int b  = bid & 3;           // xcd = bid%8 -> one batch per XCD (L2)
    const int s  = (bid >> 2) & 3;    // KV split
    const int qt = bid >> 4;          // 0..31 (128-row q tiles)
    const int tid = threadIdx.x;
    const int lane = tid & 63;
    const int wid = tid >> 6;         // wave 0..3
    const int q0 = qt * 128;
    const int l31 = lane & 31;
    const int hi  = lane >> 5;        // 0,1

    __shared__ __align__(16) unsigned short Ksm[4][32 * 128];  // 32 KiB
    __shared__ __align__(16) unsigned short Vsm[4][128 * 32];  // 32 KiB
    __shared__ float invS[128];
    __shared__ int lastS;

    // Q fragments: lane holds Q[q = q0+wid*32+l31][k = kc*16 + hi*8 .. +7]
    short8 aq[8];
    {
        const unsigned short* qrow =
            Q + ((size_t)(b * S_ + q0 + wid * 32 + l31)) * KD_;
#pragma unroll
        for (int kc = 0; kc < 8; ++kc)
            aq[kc] = *reinterpret_cast<const short8*>(&qrow[kc * 16 + hi * 8]);
    }

    f32x16 o[4];
#pragma unroll
    for (int dt = 0; dt < 4; ++dt) o[dt] = (f32x16)0.0f;
    float lsA = 0.0f, lsB = 0.0f;

    const unsigned short* Kbase = Kb + (size_t)b * S_ * KD_;
    const unsigned short* Vbase = Vt + (size_t)b * KD_ * S_;

    // stage K[32][128] + V[128][32] global tile kt into ring slot; 4 waves
    // split the granules: exactly 4 g2l16 per wave (2 K + 2 V).
    // K swizzle is 4-bit (c ^ (row&15)) -> reader 2-way conflict (free).
    auto STAGE = [&](int buf, int kt) {
#pragma unroll
        for (int i = 0; i < 2; ++i) {
            int d = i * 256 + wid * 64 + lane;         // K granule 0..511
            int row = d >> 4, c = d & 15;              // 16 granules / 128-row
            g2l16(&Kbase[(size_t)(kt * 32 + row) * KD_ + ((c ^ (row & 15)) * 8)],
                  &Ksm[buf][(i * 256 + wid * 64) * 8]);
        }
#pragma unroll
        for (int i = 0; i < 2; ++i) {
            int d = i * 256 + wid * 64 + lane;         // V granule 0..511
            int row = d >> 2, c = d & 3;               // 4 granules / 32-row
            g2l16(&Vbase[(size_t)row * S_ + kt * 32 + ((c ^ ((row >> 1) & 3)) * 8)],
                  &Vsm[buf][(i * 256 + wid * 64) * 8]);
        }
    };

    const int base = s * NIT;
    STAGE(0, base + 0);
    STAGE(1, base + 1);

    for (int it = 0; it < NIT; ++it) {
        if (it + 2 < NIT) {
            STAGE((it + 2) & 3, base + it + 2);        // 12 outstanding
            asm volatile("s_waitcnt vmcnt(8)" ::: "memory");   // drain tile it
        } else if (it + 1 < NIT) {
            asm volatile("s_waitcnt vmcnt(4)" ::: "memory");
        } else {
            asm volatile("s_waitcnt vmcnt(0)" ::: "memory");
        }
        __builtin_amdgcn_s_barrier();   // publish tile it block-wide

        const unsigned short* ksm = &Ksm[it & 3][0];
        const unsigned short* vsm = &Vsm[it & 3][0];

        // S^T = K Q^T : one 32x32 tile per wave, q = l31 lane-local.
        f32x16 sf = (f32x16)0.0f;
        __builtin_amdgcn_s_setprio(1);
#pragma unroll
        for (int kc = 0; kc < 8; ++kc) {
            short8 bk = *reinterpret_cast<const short8*>(
                &ksm[l31 * 128 + (((kc * 2 + hi) ^ (l31 & 15)) * 8)]);
            sf = mfma32_bf16(bk, aq[kc], sf);
        }
        __builtin_amdgcn_s_setprio(0);

        // p = exp2(s_pre), per-lane row sum (2 chains); pack P to bf16 PV
        // A-frags in-register: kv(r) = (r&3)+8*(r>>2)+4*hi.
        float p[16];
#pragma unroll
        for (int r = 0; r < 16; ++r) {
            p[r] = exp2f(sf[r]);
            if (r & 1) lsB += p[r]; else lsA += p[r];
        }

        short8 pa[2];
#pragma unroll
        for (int c = 0; c < 2; ++c) {
            u32x4 wv;
#pragma unroll
            for (int e = 0; e < 2; ++e) {
                unsigned int X = cvt_pk_bf16(p[8 * c + 2 * e], p[8 * c + 2 * e + 1]);
                unsigned int Y = cvt_pk_bf16(p[8 * c + 4 + 2 * e], p[8 * c + 4 + 2 * e + 1]);
                unsigned int Ss = hi ? X : Y;
                unsigned int T = __shfl_xor(Ss, 32);
                wv[e]     = hi ? T : X;
                wv[2 + e] = hi ? Y : T;
            }
            pa[c] = __builtin_bit_cast(short8, wv);
        }

        // O += P V : A = P (q=l31 rows, kv-chunk c), B = Vt rows (d cols).
        __builtin_amdgcn_s_setprio(1);
#pragma unroll
        for (int c = 0; c < 2; ++c)
#pragma unroll
            for (int dt = 0; dt < 4; ++dt) {
                int row = dt * 32 + l31;
                short8 bv = *reinterpret_cast<const short8*>(
                    &vsm[row * 32 + (((c * 2 + hi) ^ ((row >> 1) & 3)) * 8)]);
                o[dt] = mfma32_bf16(pa[c], bv, o[dt]);
            }
        __builtin_amdgcn_s_setprio(0);
        // no trailing barrier: ring depth 4 + barrier chain provides WAR
    }

    float lsum = lsA + lsB;
    lsum += __shfl_xor(lsum, 32);     // other kv half lives in lane^32

    // write bf16 partial tile (128x128) + f32 sums (disjoint per block)
    const int tile = (qt << 2) | b;   // 0..127
    unsigned short* Po = part16 + ((size_t)tile * NSPL + s) * 16384;
#pragma unroll
    for (int r = 0; r < 16; ++r) {
        int row = wid * 32 + (r & 3) + 8 * (r >> 2) + 4 * hi;
#pragma unroll
        for (int dt = 0; dt < 4; ++dt)
            Po[row * 128 + dt * 32 + l31] = f2bf(o[dt][r]);
    }
    if (hi == 0)
        lsumP[((size_t)tile * NSPL + s) * 128 + wid * 32 + l31] = lsum;

    // --- fused merge: last split-block for this tile does it -------------
    __threadfence();                              // release partials
    if (tid == 0) lastS = (atomicAdd(&cnt[tile], 1) == NSPL - 1);
    __syncthreads();
    if (!lastS) return;
    __threadfence();                              // acquire others' partials

    if (tid < 128) {
        const float* lp = lsumP + (size_t)tile * (NSPL * 128);
        float t = 0.0f;
#pragma unroll
        for (int ss = 0; ss < NSPL; ++ss) t += lp[ss * 128 + tid];
        invS[tid] = 1.0f / t;
    }
    __syncthreads();

    const unsigned short* pall = part16 + (size_t)tile * NSPL * 16384;
    float* Ob = Out + ((size_t)b * S_ + (size_t)q0) * KD_;
#pragma unroll
    for (int i = 0; i < 8; ++i) {
        int g = tid + i * 256;        // short8 group, 0..2047 (128x128 tile)
        int row = g >> 4;
        float acc8[8] = {0, 0, 0, 0, 0, 0, 0, 0};
#pragma unroll
        for (int ss = 0; ss < NSPL; ++ss) {
            short8 v = *reinterpret_cast<const short8*>(&pall[ss * 16384 + g * 8]);
#pragma unroll
            for (int j = 0; j < 8; ++j) {
                unsigned int u = ((unsigned int)(unsigned short)v[j]) << 16;
                acc8[j] += __uint_as_float(u);
            }
        }
        float iv = invS[row];
        float4 r0v, r1v;
        r0v.x = acc8[0] * iv; r0v.y = acc8[1] * iv;
        r0v.z = acc8[2] * iv; r0v.w = acc8[3] * iv;
        r1v.x = acc8[4] * iv; r1v.y = acc8[5] * iv;
        r1v.z = acc8[6] * iv; r1v.w = acc8[7] * iv;
        *reinterpret_cast<float4*>(&Ob[g * 8]) = r0v;
        *reinterpret_cast<float4*>(&Ob[g * 8 + 4]) = r1v;
    }
}

// ---------------------------------------------------------------------------
// Fallback (R8, exp2f): single-block-per-qtile, in-block merge. Used if
// ws_size is too small for the split partials.
__global__ __launch_bounds__(512, 2) void attn_kernel(
        const unsigned short* __restrict__ Q,
        const unsigned short* __restrict__ Kb,
        const unsigned short* __restrict__ Vt,
        float* __restrict__ Out) {
    const int bid = blockIdx.x;
    const int b  = bid & 3;
    const int qt = bid >> 2;
    const int tid = threadIdx.x;
    const int lane = tid & 63;
    const int wid = tid >> 6;
    const int grp = wid >> 1;
    const int wg  = wid & 1;
    const int q0 = qt * 64;
    const int l31 = lane & 31;
    const int hi  = lane >> 5;

    __shared__ __align__(16) unsigned char lds_raw[131072];
    unsigned short* KsmA = (unsigned short*)lds_raw;
    unsigned short* VsmA = (unsigned short*)(lds_raw + 65536);

    short8 aq[8];
    {
        const unsigned short* qrow =
            Q + ((size_t)(b * S_ + q0 + wg * 32 + l31)) * KD_;
#pragma unroll
        for (int kc = 0; kc < 8; ++kc)
            aq[kc] = *reinterpret_cast<const short8*>(&qrow[kc * 16 + hi * 8]);
    }

    f32x16 o[4];
#pragma unroll
    for (int dt = 0; dt < 4; ++dt) o[dt] = (f32x16)0.0f;
    float lsum = 0.0f;

    const unsigned short* Kbase = Kb + (size_t)b * S_ * KD_;
    const unsigned short* Vbase = Vt + (size_t)b * KD_ * S_;

    unsigned short* Kgrp = KsmA + grp * 2 * 4096;
    unsigned short* Vgrp = VsmA + grp * 2 * 4096;

    auto STAGE = [&](int buf, int kt) {
#pragma unroll
        for (int i = 0; i < 4; ++i) {
            int d = i * 128 + wg * 64 + lane;
            int row = d >> 4, c = d & 15;
            g2l16(&Kbase[(size_t)(kt * 32 + row) * KD_ + ((c ^ (row & 15)) * 8)],
                  &Kgrp[(buf * 512 + i * 128 + wg * 64) * 8]);
        }
#pragma unroll
        for (int i = 0; i < 4; ++i) {
            int d = i * 128 + wg * 64 + lane;
            int row = d >> 2, c = d & 3;
            g2l16(&Vbase[(size_t)row * S_ + kt * 32 + ((c ^ ((row >> 1) & 3)) * 8)],
                  &Vgrp[(buf * 512 + i * 128 + wg * 64) * 8]);
        }
    };

    int cur = 0;
    STAGE(0, grp);
    __syncthreads();

    for (int it = 0; it < 32; ++it) {
        if (it < 31) STAGE(cur ^ 1, (it + 1) * 4 + grp);

        const unsigned short* ksm = Kgrp + cur * 4096;
        const unsigned short* vsm = Vgrp + cur * 4096;

        f32x16 sf = (f32x16)0.0f;
        __builtin_amdgcn_s_setprio(1);
#pragma unroll
        for (int kc = 0; kc < 8; ++kc) {
            short8 bk = *reinterpret_cast<const short8*>(
                &ksm[l31 * 128 + (((kc * 2 + hi) ^ (l31 & 15)) * 8)]);
            sf = mfma32_bf16(bk, aq[kc], sf);
        }
        __builtin_amdgcn_s_setprio(0);

        float p[16];
#pragma unroll
        for (int r = 0; r < 16; ++r) {
            p[r] = exp2f(sf[r]);
            lsum += p[r];
        }

        short8 pa[2];
#pragma unroll
        for (int c = 0; c < 2; ++c) {
            u32x4 wv;
#pragma unroll
            for (int e = 0; e < 2; ++e) {
                unsigned int X = cvt_pk_bf16(p[8 * c + 2 * e], p[8 * c + 2 * e + 1]);
                unsigned int Y = cvt_pk_bf16(p[8 * c + 4 + 2 * e], p[8 * c + 4 + 2 * e + 1]);
                unsigned int Ss = hi ? X : Y;
                unsigned int T = __shfl_xor(Ss, 32);
                wv[e]     = hi ? T : X;
                wv[2 + e] = hi ? Y : T;
            }
            pa[c] = __builtin_bit_cast(short8, wv);
        }

        __builtin_amdgcn_s_setprio(1);
#pragma unroll
        for (int c = 0; c < 2; ++c)
#pragma unroll
            for (int dt = 0; dt < 4; ++dt) {
                int row = dt * 32 + l31;
                short8 bv = *reinterpret_cast<const short8*>(
                    &vsm[row * 32 + (((c * 2 + hi) ^ ((row >> 1) & 3)) * 8)]);
                o[dt] = mfma32_bf16(pa[c], bv, o[dt]);
            }
        __builtin_amdgcn_s_setprio(0);

        __syncthreads();
        cur ^= 1;
    }

    lsum += __shfl_xor(lsum, 32);

    float* scratch = (float*)lds_raw;
    float* lsumS   = (float*)(lds_raw + 98304);
    __syncthreads();
    if (grp >= 1) {
        int base = (grp - 1) * 8192;
#pragma unroll
        for (int dt = 0; dt < 4; ++dt)
#pragma unroll
            for (int r = 0; r < 16; ++r) {
                int row = wg * 32 + (r & 3) + 8 * (r >> 2) + 4 * hi;
                scratch[base + row * 128 + dt * 32 + l31] = o[dt][r];
            }
    }
    if (hi == 0) lsumS[grp * 64 + wg * 32 + l31] = lsum;
    __syncthreads();
    if (grp == 0) {
        float* Ob = Out + (size_t)b * S_ * KD_;
#pragma unroll
        for (int r = 0; r < 16; ++r) {
            int row = wg * 32 + (r & 3) + 8 * (r >> 2) + 4 * hi;
            float inv = 1.0f / (lsumS[row] + lsumS[64 + row] +
                                lsumS[128 + row] + lsumS[192 + row]);
#pragma unroll
            for (int dt = 0; dt < 4; ++dt) {
                int col = dt * 32 + l31;
                int idx = row * 128 + col;
                float v = o[dt][r] + scratch[idx] + scratch[8192 + idx] +
                          scratch[16384 + idx];
                Ob[(size_t)(q0 + row) * KD_ + col] = v * inv;
            }
        }
    }
}

// ---------------------------------------------------------------------------
extern "C" void kernel_launch(void* const* d_in, const int* in_sizes, int n_in,
                              void* d_out, int out_size, void* d_ws, size_t ws_size,
                              hipStream_t stream) {
    const float* X  = (const float*)d_in[0];
    const float* Wq = (const float*)d_in[1];
    const float* Wk = (const float*)d_in[2];
    const float* Wv = (const float*)d_in[3];
    float* Out = (float*)d_out;

    unsigned short* Wt  = (unsigned short*)d_ws;                    // 768 KiB
    unsigned short* Q16 = (unsigned short*)((char*)d_ws + 786432);  // 4 MiB
    unsigned short* K16 = Q16 + (size_t)16384 * 128;                // 4 MiB
    unsigned short* V16 = K16 + (size_t)16384 * 128;                // 4 MiB (Vt)
    unsigned short* part16 = (unsigned short*)((char*)d_ws + 13369344); // 16 MiB
    float* lsumP = (float*)((char*)d_ws + 13369344 + 16777216);     // 256 KiB
    int*   cnt   = (int*)((char*)d_ws + 13369344 + 16777216 + 262144); // 512 B
    const size_t ws_need = 13369344 + 16777216 + 262144 + 512;

    hipLaunchKernelGGL(convert_w_kernel, dim3(192), dim3(256), 0, stream,
                       Wq, Wk, Wv, Wt);
    hipLaunchKernelGGL(proj_kernel, dim3(384), dim3(256), 0, stream,
                       X, Wt, Q16, K16, V16);
    if (ws_size >= ws_need) {
        hipMemsetAsync(cnt, 0, 512, stream);      // reset merge counters
        hipLaunchKernelGGL(attn_split_kernel, dim3(512), dim3(256), 0, stream,
                           Q16, K16, V16, part16, lsumP, cnt, Out);
    } else {
        hipLaunchKernelGGL(attn_kernel, dim3(256), dim3(512), 0, stream,
                           Q16, K16, V16, Out);
    }
}

// Round 15
// 118.861 us; speedup vs baseline: 1.5322x; 1.5322x over previous
//
#include <hip/hip_runtime.h>
#include <hip/hip_bf16.h>
#include <math.h>

#define B_  4
#define S_  4096
#define D_  1024
#define KD_ 128
#define NSPL 4            // KV splits
#define NIT  (S_ / NSPL / 32)  // 32 iterations of KBLK=32

typedef __attribute__((ext_vector_type(8))) short short8;
typedef __attribute__((ext_vector_type(4))) float f32x4;
typedef __attribute__((ext_vector_type(16))) float f32x16;
typedef __attribute__((ext_vector_type(4))) unsigned short us4;
typedef __attribute__((ext_vector_type(4))) unsigned int u32x4;

__device__ __forceinline__ unsigned short f2bf(float f) {
    __hip_bfloat16 h = __float2bfloat16(f);
    return *reinterpret_cast<unsigned short*>(&h);
}

__device__ __forceinline__ f32x4 mfma_bf16(short8 a, short8 b, f32x4 c) {
    return __builtin_amdgcn_mfma_f32_16x16x32_bf16(a, b, c, 0, 0, 0);
}

__device__ __forceinline__ f32x16 mfma32_bf16(short8 a, short8 b, f32x16 c) {
    return __builtin_amdgcn_mfma_f32_32x32x16_bf16(a, b, c, 0, 0, 0);
}

__device__ __forceinline__ unsigned int cvt_pk_bf16(float lo, float hi_) {
    unsigned int r;
    asm("v_cvt_pk_bf16_f32 %0, %1, %2" : "=v"(r) : "v"(lo), "v"(hi_));
    return r;
}

__device__ __forceinline__ void g2l16(const void* g, void* l) {
    __builtin_amdgcn_global_load_lds(
        (const __attribute__((address_space(1))) unsigned int*)g,
        (__attribute__((address_space(3))) unsigned int*)l, 16, 0, 0);
}

// ---------------------------------------------------------------------------
// Convert weights [D,128] fp32 -> Wt [3][128][D] bf16 (transposed).
// Q weight folds in log2(e)/sqrt(128) so softmax can use native exp2.
__global__ void convert_w_kernel(const float* __restrict__ wq,
                                 const float* __restrict__ wk,
                                 const float* __restrict__ wv,
                                 unsigned short* __restrict__ wt) {
    int t = blockIdx.x * 256 + threadIdx.x;       // 0..49151
    int w = t >> 14;
    int r = t & 16383;
    int n = r & 127;
    int k8 = r >> 7;                               // 0..127
    const float* src = (w == 0) ? wq : (w == 1) ? wk : wv;
    float scale = (w == 0) ? 0.12751725551033443f : 1.0f;  // log2e/sqrt(128)
    short8 v;
#pragma unroll
    for (int i = 0; i < 8; ++i)
        v[i] = (short)f2bf(src[(size_t)(k8 * 8 + i) * KD_ + n] * scale);
    *reinterpret_cast<short8*>(&wt[(size_t)w * KD_ * D_ + (size_t)n * D_ + k8 * 8]) = v;
}

// ---------------------------------------------------------------------------
// Projection GEMM: C[16384,128] = X[16384,1024] @ W.  NT form, Wt[128][1024].
// R15: double-buffered A/B, B staged via global_load_lds (no VGPR roundtrip),
// A loads issued at loop top (T14: HBM latency hides under 32 MFMA), one
// __syncthreads per k-step. Tsm overlays the A buffers in the epilogue so
// LDS stays 64 KB -> 2 blocks/CU, 384 blocks = one round.
// bid = (m&7) + 8*which + 24*(m>>3): 3 which-blocks of one mtile share an XCD.
__global__ __launch_bounds__(256) void proj_kernel(
        const float* __restrict__ X, const unsigned short* __restrict__ Wt,
        unsigned short* __restrict__ Qo, unsigned short* __restrict__ Ko,
        unsigned short* __restrict__ Vt) {
    const int bid = blockIdx.x;
    const int g = bid / 24;
    const int local = bid - g * 24;
    const int which = local >> 3;
    const int mtile = g * 8 + (local & 7);
    const int m0 = mtile * 128;
    const int tid = threadIdx.x;
    const int lane = tid & 63;
    const int wid = tid >> 6;
    const int wr = wid >> 1, wc = wid & 1;
    const int l15 = lane & 15, l4 = lane >> 4;

    __shared__ __align__(16) unsigned short Asm[2][128 * 64];  // 32 KiB
    __shared__ __align__(16) unsigned short Bsm[2][128 * 64];  // 32 KiB

    const unsigned short* W = Wt + (size_t)which * KD_ * D_;

    f32x4 acc[4][4];
#pragma unroll
    for (int r = 0; r < 4; ++r)
#pragma unroll
        for (int c = 0; c < 4; ++c) acc[r][c] = (f32x4)0.0f;

    float4 xa[8];
    auto LOADA = [&](int ks) {
#pragma unroll
        for (int i = 0; i < 8; ++i) {
            int f = tid + i * 256;
            int row = f >> 4, c4 = f & 15;
            xa[i] = *reinterpret_cast<const float4*>(
                &X[(size_t)(m0 + row) * D_ + ks * 64 + c4 * 4]);
        }
    };
    auto WRITEA = [&](int buf) {
#pragma unroll
        for (int i = 0; i < 8; ++i) {
            int f = tid + i * 256;
            int row = f >> 4, c4 = f & 15;
            us4 h;
            h.x = f2bf(xa[i].x); h.y = f2bf(xa[i].y);
            h.z = f2bf(xa[i].z); h.w = f2bf(xa[i].w);
            *reinterpret_cast<us4*>(&Asm[buf][row * 64 + c4 * 4]) = h;
        }
    };
    auto STAGEB = [&](int buf, int ks) {
#pragma unroll
        for (int i = 0; i < 4; ++i) {
            int gg = i * 256 + tid;        // granule 0..1023
            int n = gg >> 3, c8 = gg & 7;
            g2l16(&W[(size_t)n * D_ + ks * 64 + c8 * 8],
                  &Bsm[buf][(i * 256 + wid * 64) * 8]);
        }
    };

    LOADA(0);
    STAGEB(0, 0);
    WRITEA(0);
    __syncthreads();

    int buf = 0;
    for (int ks = 0; ks < 16; ++ks) {
        if (ks < 15) { LOADA(ks + 1); STAGEB(buf ^ 1, ks + 1); }

        short8 a[4][2], b[4][2];
#pragma unroll
        for (int rt = 0; rt < 4; ++rt)
#pragma unroll
            for (int kc = 0; kc < 2; ++kc)
                a[rt][kc] = *reinterpret_cast<const short8*>(
                    &Asm[buf][(wr * 64 + rt * 16 + l15) * 64 + kc * 32 + l4 * 8]);
#pragma unroll
        for (int ct = 0; ct < 4; ++ct)
#pragma unroll
            for (int kc = 0; kc < 2; ++kc)
                b[ct][kc] = *reinterpret_cast<const short8*>(
                    &Bsm[buf][(wc * 64 + ct * 16 + l15) * 64 + kc * 32 + l4 * 8]);
        __builtin_amdgcn_s_setprio(1);
#pragma unroll
        for (int kc = 0; kc < 2; ++kc)
#pragma unroll
            for (int rt = 0; rt < 4; ++rt)
#pragma unroll
                for (int ct = 0; ct < 4; ++ct)
                    acc[rt][ct] = mfma_bf16(a[rt][kc], b[ct][kc], acc[rt][ct]);
        __builtin_amdgcn_s_setprio(0);

        if (ks < 15) WRITEA(buf ^ 1);
        __syncthreads();
        buf ^= 1;
    }

    if (which < 2) {
        unsigned short* O = (which == 0) ? Qo : Ko;
#pragma unroll
        for (int rt = 0; rt < 4; ++rt)
#pragma unroll
            for (int ct = 0; ct < 4; ++ct)
#pragma unroll
                for (int j = 0; j < 4; ++j) {
                    int row = m0 + wr * 64 + rt * 16 + l4 * 4 + j;
                    int col = wc * 64 + ct * 16 + l15;
                    O[(size_t)row * KD_ + col] = f2bf(acc[rt][ct][j]);
                }
    } else {
        // transpose through LDS (Tsm overlays the two A buffers, 32 KiB)
        unsigned short* Tsm = &Asm[0][0];
#pragma unroll
        for (int rt = 0; rt < 4; ++rt)
#pragma unroll
            for (int ct = 0; ct < 4; ++ct)
#pragma unroll
                for (int j = 0; j < 4; ++j) {
                    int row = wr * 64 + rt * 16 + l4 * 4 + j;  // s-local
                    int col = wc * 64 + ct * 16 + l15;          // n
                    Tsm[col * 128 + row] = f2bf(acc[rt][ct][j]);
                }
        __syncthreads();
        int bb = m0 >> 12;
        int s0 = m0 & 4095;
#pragma unroll
        for (int i = 0; i < 8; ++i) {
            int gg = tid + i * 256;
            int n = gg >> 4, s8 = gg & 15;
            *reinterpret_cast<short8*>(
                &Vt[(size_t)bb * KD_ * S_ + (size_t)n * S_ + s0 + s8 * 8]) =
                *reinterpret_cast<short8*>(&Tsm[n * 128 + s8 * 8]);
        }
    }
}

// ---------------------------------------------------------------------------
// R15 flash attention = R13 (split-KV x4, 4-deep ring + counted vmcnt,
// separate merge) + 4-bit K swizzle (R14-verified: conflicts 4.19M -> 2.09M).
__global__ __launch_bounds__(256, 2) void attn_split_kernel(
        const unsigned short* __restrict__ Q,
        const unsigned short* __restrict__ Kb,
        const unsigned short* __restrict__ Vt,
        unsigned short* __restrict__ part16, float* __restrict__ lsumP) {
    const int bid = blockIdx.x;       // 0..511
    const int b  = bid & 3;           // xcd = bid%8 -> one batch per XCD (L2)
    const int s  = (bid >> 2) & 3;    // KV split
    const int qt = bid >> 4;          // 0..31 (128-row q tiles)
    const int tid = threadIdx.x;
    const int lane = tid & 63;
    const int wid = tid >> 6;         // wave 0..3
    const int q0 = qt * 128;
    const int l31 = lane & 31;
    const int hi  = lane >> 5;        // 0,1

    __shared__ __align__(16) unsigned short Ksm[4][32 * 128];  // 32 KiB
    __shared__ __align__(16) unsigned short Vsm[4][128 * 32];  // 32 KiB

    // Q fragments: lane holds Q[q = q0+wid*32+l31][k = kc*16 + hi*8 .. +7]
    short8 aq[8];
    {
        const unsigned short* qrow =
            Q + ((size_t)(b * S_ + q0 + wid * 32 + l31)) * KD_;
#pragma unroll
        for (int kc = 0; kc < 8; ++kc)
            aq[kc] = *reinterpret_cast<const short8*>(&qrow[kc * 16 + hi * 8]);
    }

    f32x16 o[4];
#pragma unroll
    for (int dt = 0; dt < 4; ++dt) o[dt] = (f32x16)0.0f;
    float lsA = 0.0f, lsB = 0.0f;

    const unsigned short* Kbase = Kb + (size_t)b * S_ * KD_;
    const unsigned short* Vbase = Vt + (size_t)b * KD_ * S_;

    // stage K[32][128] + V[128][32] global tile kt into ring slot; 4 waves
    // split the granules: exactly 4 g2l16 per wave (2 K + 2 V).
    // K swizzle is 4-bit (c ^ (row&15)) -> reader 2-way conflict (free).
    auto STAGE = [&](int buf, int kt) {
#pragma unroll
        for (int i = 0; i < 2; ++i) {
            int d = i * 256 + wid * 64 + lane;         // K granule 0..511
            int row = d >> 4, c = d & 15;              // 16 granules / 128-row
            g2l16(&Kbase[(size_t)(kt * 32 + row) * KD_ + ((c ^ (row & 15)) * 8)],
                  &Ksm[buf][(i * 256 + wid * 64) * 8]);
        }
#pragma unroll
        for (int i = 0; i < 2; ++i) {
            int d = i * 256 + wid * 64 + lane;         // V granule 0..511
            int row = d >> 2, c = d & 3;               // 4 granules / 32-row
            g2l16(&Vbase[(size_t)row * S_ + kt * 32 + ((c ^ ((row >> 1) & 3)) * 8)],
                  &Vsm[buf][(i * 256 + wid * 64) * 8]);
        }
    };

    const int base = s * NIT;
    STAGE(0, base + 0);
    STAGE(1, base + 1);

    for (int it = 0; it < NIT; ++it) {
        if (it + 2 < NIT) {
            STAGE((it + 2) & 3, base + it + 2);        // 12 outstanding
            asm volatile("s_waitcnt vmcnt(8)" ::: "memory");   // drain tile it
        } else if (it + 1 < NIT) {
            asm volatile("s_waitcnt vmcnt(4)" ::: "memory");
        } else {
            asm volatile("s_waitcnt vmcnt(0)" ::: "memory");
        }
        __builtin_amdgcn_s_barrier();   // publish tile it block-wide

        const unsigned short* ksm = &Ksm[it & 3][0];
        const unsigned short* vsm = &Vsm[it & 3][0];

        // S^T = K Q^T : one 32x32 tile per wave, q = l31 lane-local.
        f32x16 sf = (f32x16)0.0f;
        __builtin_amdgcn_s_setprio(1);
#pragma unroll
        for (int kc = 0; kc < 8; ++kc) {
            short8 bk = *reinterpret_cast<const short8*>(
                &ksm[l31 * 128 + (((kc * 2 + hi) ^ (l31 & 15)) * 8)]);
            sf = mfma32_bf16(bk, aq[kc], sf);
        }
        __builtin_amdgcn_s_setprio(0);

        // p = exp2(s_pre), per-lane row sum (2 chains); pack P to bf16 PV
        // A-frags in-register: kv(r) = (r&3)+8*(r>>2)+4*hi.
        float p[16];
#pragma unroll
        for (int r = 0; r < 16; ++r) {
            p[r] = exp2f(sf[r]);
            if (r & 1) lsB += p[r]; else lsA += p[r];
        }

        short8 pa[2];
#pragma unroll
        for (int c = 0; c < 2; ++c) {
            u32x4 wv;
#pragma unroll
            for (int e = 0; e < 2; ++e) {
                unsigned int X = cvt_pk_bf16(p[8 * c + 2 * e], p[8 * c + 2 * e + 1]);
                unsigned int Y = cvt_pk_bf16(p[8 * c + 4 + 2 * e], p[8 * c + 4 + 2 * e + 1]);
                unsigned int Ss = hi ? X : Y;
                unsigned int T = __shfl_xor(Ss, 32);
                wv[e]     = hi ? T : X;
                wv[2 + e] = hi ? Y : T;
            }
            pa[c] = __builtin_bit_cast(short8, wv);
        }

        // O += P V : A = P (q=l31 rows, kv-chunk c), B = Vt rows (d cols).
        __builtin_amdgcn_s_setprio(1);
#pragma unroll
        for (int c = 0; c < 2; ++c)
#pragma unroll
            for (int dt = 0; dt < 4; ++dt) {
                int row = dt * 32 + l31;
                short8 bv = *reinterpret_cast<const short8*>(
                    &vsm[row * 32 + (((c * 2 + hi) ^ ((row >> 1) & 3)) * 8)]);
                o[dt] = mfma32_bf16(pa[c], bv, o[dt]);
            }
        __builtin_amdgcn_s_setprio(0);
        // no trailing barrier: ring depth 4 + barrier chain provides WAR
    }

    float lsum = lsA + lsB;
    lsum += __shfl_xor(lsum, 32);     // other kv half lives in lane^32

    // write bf16 partial tile (128x128) + f32 sums (disjoint per block)
    const int tile = (qt << 2) | b;   // 0..127
    unsigned short* Po = part16 + ((size_t)tile * NSPL + s) * 16384;
#pragma unroll
    for (int r = 0; r < 16; ++r) {
        int row = wid * 32 + (r & 3) + 8 * (r >> 2) + 4 * hi;
#pragma unroll
        for (int dt = 0; dt < 4; ++dt)
            Po[row * 128 + dt * 32 + l31] = f2bf(o[dt][r]);
    }
    if (hi == 0)
        lsumP[((size_t)tile * NSPL + s) * 128 + wid * 32 + l31] = lsum;
}

// ---------------------------------------------------------------------------
// Merge 4 bf16 KV-split partials: out = sum(part_s) / sum(lsum_s).
// 256 blocks, each merges a 64-row half of one 128x128 tile.
__global__ __launch_bounds__(256) void merge_kernel(
        const unsigned short* __restrict__ part16,
        const float* __restrict__ lsumP, float* __restrict__ Out) {
    const int th = blockIdx.x;        // 0..255
    const int tile = th >> 1;         // 0..127 = qt*4 + b
    const int half = th & 1;
    const int b = tile & 3, qt = tile >> 2;
    const int r0 = half * 64;
    const int tid = threadIdx.x;
    __shared__ float inv[64];
    if (tid < 64) {
        const float* lp = lsumP + (size_t)tile * (NSPL * 128) + r0;
        float t = 0.0f;
#pragma unroll
        for (int s = 0; s < NSPL; ++s) t += lp[s * 128 + tid];
        inv[tid] = 1.0f / t;
    }
    __syncthreads();
    const unsigned short* p = part16 + (size_t)tile * NSPL * 16384 + r0 * 128;
    float* Ob = Out + ((size_t)b * S_ + qt * 128 + r0) * KD_;
#pragma unroll
    for (int i = 0; i < 4; ++i) {
        int g = tid + i * 256;        // short8 group, 0..1023 (64x128 half)
        int row = g >> 4;
        float acc8[8] = {0, 0, 0, 0, 0, 0, 0, 0};
#pragma unroll
        for (int s = 0; s < NSPL; ++s) {
            short8 v = *reinterpret_cast<const short8*>(&p[s * 16384 + g * 8]);
#pragma unroll
            for (int j = 0; j < 8; ++j) {
                unsigned int u = ((unsigned int)(unsigned short)v[j]) << 16;
                acc8[j] += __uint_as_float(u);
            }
        }
        float iv = inv[row];
        float4 r0v, r1v;
        r0v.x = acc8[0] * iv; r0v.y = acc8[1] * iv;
        r0v.z = acc8[2] * iv; r0v.w = acc8[3] * iv;
        r1v.x = acc8[4] * iv; r1v.y = acc8[5] * iv;
        r1v.z = acc8[6] * iv; r1v.w = acc8[7] * iv;
        *reinterpret_cast<float4*>(&Ob[g * 8]) = r0v;
        *reinterpret_cast<float4*>(&Ob[g * 8 + 4]) = r1v;
    }
}

// ---------------------------------------------------------------------------
// Fallback (R8-style, exp2f, 4-bit K swizzle): single-block-per-qtile,
// in-block merge. Used if ws_size is too small for the split partials.
__global__ __launch_bounds__(512, 2) void attn_kernel(
        const unsigned short* __restrict__ Q,
        const unsigned short* __restrict__ Kb,
        const unsigned short* __restrict__ Vt,
        float* __restrict__ Out) {
    const int bid = blockIdx.x;
    const int b  = bid & 3;
    const int qt = bid >> 2;
    const int tid = threadIdx.x;
    const int lane = tid & 63;
    const int wid = tid >> 6;
    const int grp = wid >> 1;
    const int wg  = wid & 1;
    const int q0 = qt * 64;
    const int l31 = lane & 31;
    const int hi  = lane >> 5;

    __shared__ __align__(16) unsigned char lds_raw[131072];
    unsigned short* KsmA = (unsigned short*)lds_raw;
    unsigned short* VsmA = (unsigned short*)(lds_raw + 65536);

    short8 aq[8];
    {
        const unsigned short* qrow =
            Q + ((size_t)(b * S_ + q0 + wg * 32 + l31)) * KD_;
#pragma unroll
        for (int kc = 0; kc < 8; ++kc)
            aq[kc] = *reinterpret_cast<const short8*>(&qrow[kc * 16 + hi * 8]);
    }

    f32x16 o[4];
#pragma unroll
    for (int dt = 0; dt < 4; ++dt) o[dt] = (f32x16)0.0f;
    float lsum = 0.0f;

    const unsigned short* Kbase = Kb + (size_t)b * S_ * KD_;
    const unsigned short* Vbase = Vt + (size_t)b * KD_ * S_;

    unsigned short* Kgrp = KsmA + grp * 2 * 4096;
    unsigned short* Vgrp = VsmA + grp * 2 * 4096;

    auto STAGE = [&](int buf, int kt) {
#pragma unroll
        for (int i = 0; i < 4; ++i) {
            int d = i * 128 + wg * 64 + lane;
            int row = d >> 4, c = d & 15;
            g2l16(&Kbase[(size_t)(kt * 32 + row) * KD_ + ((c ^ (row & 15)) * 8)],
                  &Kgrp[(buf * 512 + i * 128 + wg * 64) * 8]);
        }
#pragma unroll
        for (int i = 0; i < 4; ++i) {
            int d = i * 128 + wg * 64 + lane;
            int row = d >> 2, c = d & 3;
            g2l16(&Vbase[(size_t)row * S_ + kt * 32 + ((c ^ ((row >> 1) & 3)) * 8)],
                  &Vgrp[(buf * 512 + i * 128 + wg * 64) * 8]);
        }
    };

    int cur = 0;
    STAGE(0, grp);
    __syncthreads();

    for (int it = 0; it < 32; ++it) {
        if (it < 31) STAGE(cur ^ 1, (it + 1) * 4 + grp);

        const unsigned short* ksm = Kgrp + cur * 4096;
        const unsigned short* vsm = Vgrp + cur * 4096;

        f32x16 sf = (f32x16)0.0f;
        __builtin_amdgcn_s_setprio(1);
#pragma unroll
        for (int kc = 0; kc < 8; ++kc) {
            short8 bk = *reinterpret_cast<const short8*>(
                &ksm[l31 * 128 + (((kc * 2 + hi) ^ (l31 & 15)) * 8)]);
            sf = mfma32_bf16(bk, aq[kc], sf);
        }
        __builtin_amdgcn_s_setprio(0);

        float p[16];
#pragma unroll
        for (int r = 0; r < 16; ++r) {
            p[r] = exp2f(sf[r]);
            lsum += p[r];
        }

        short8 pa[2];
#pragma unroll
        for (int c = 0; c < 2; ++c) {
            u32x4 wv;
#pragma unroll
            for (int e = 0; e < 2; ++e) {
                unsigned int X = cvt_pk_bf16(p[8 * c + 2 * e], p[8 * c + 2 * e + 1]);
                unsigned int Y = cvt_pk_bf16(p[8 * c + 4 + 2 * e], p[8 * c + 4 + 2 * e + 1]);
                unsigned int Ss = hi ? X : Y;
                unsigned int T = __shfl_xor(Ss, 32);
                wv[e]     = hi ? T : X;
                wv[2 + e] = hi ? Y : T;
            }
            pa[c] = __builtin_bit_cast(short8, wv);
        }

        __builtin_amdgcn_s_setprio(1);
#pragma unroll
        for (int c = 0; c < 2; ++c)
#pragma unroll
            for (int dt = 0; dt < 4; ++dt) {
                int row = dt * 32 + l31;
                short8 bv = *reinterpret_cast<const short8*>(
                    &vsm[row * 32 + (((c * 2 + hi) ^ ((row >> 1) & 3)) * 8)]);
                o[dt] = mfma32_bf16(pa[c], bv, o[dt]);
            }
        __builtin_amdgcn_s_setprio(0);

        __syncthreads();
        cur ^= 1;
    }

    lsum += __shfl_xor(lsum, 32);

    float* scratch = (float*)lds_raw;
    float* lsumS   = (float*)(lds_raw + 98304);
    __syncthreads();
    if (grp >= 1) {
        int base = (grp - 1) * 8192;
#pragma unroll
        for (int dt = 0; dt < 4; ++dt)
#pragma unroll
            for (int r = 0; r < 16; ++r) {
                int row = wg * 32 + (r & 3) + 8 * (r >> 2) + 4 * hi;
                scratch[base + row * 128 + dt * 32 + l31] = o[dt][r];
            }
    }
    if (hi == 0) lsumS[grp * 64 + wg * 32 + l31] = lsum;
    __syncthreads();
    if (grp == 0) {
        float* Ob = Out + (size_t)b * S_ * KD_;
#pragma unroll
        for (int r = 0; r < 16; ++r) {
            int row = wg * 32 + (r & 3) + 8 * (r >> 2) + 4 * hi;
            float inv = 1.0f / (lsumS[row] + lsumS[64 + row] +
                                lsumS[128 + row] + lsumS[192 + row]);
#pragma unroll
            for (int dt = 0; dt < 4; ++dt) {
                int col = dt * 32 + l31;
                int idx = row * 128 + col;
                float v = o[dt][r] + scratch[idx] + scratch[8192 + idx] +
                          scratch[16384 + idx];
                Ob[(size_t)(q0 + row) * KD_ + col] = v * inv;
            }
        }
    }
}

// ---------------------------------------------------------------------------
extern "C" void kernel_launch(void* const* d_in, const int* in_sizes, int n_in,
                              void* d_out, int out_size, void* d_ws, size_t ws_size,
                              hipStream_t stream) {
    const float* X  = (const float*)d_in[0];
    const float* Wq = (const float*)d_in[1];
    const float* Wk = (const float*)d_in[2];
    const float* Wv = (const float*)d_in[3];
    float* Out = (float*)d_out;

    unsigned short* Wt  = (unsigned short*)d_ws;                    // 768 KiB
    unsigned short* Q16 = (unsigned short*)((char*)d_ws + 786432);  // 4 MiB
    unsigned short* K16 = Q16 + (size_t)16384 * 128;                // 4 MiB
    unsigned short* V16 = K16 + (size_t)16384 * 128;                // 4 MiB (Vt)
    unsigned short* part16 = (unsigned short*)((char*)d_ws + 13369344); // 16 MiB
    float* lsumP = (float*)((char*)d_ws + 13369344 + 16777216);     // 256 KiB
    const size_t ws_need = 13369344 + 16777216 + 262144;            // ~30.4 MB

    hipLaunchKernelGGL(convert_w_kernel, dim3(192), dim3(256), 0, stream,
                       Wq, Wk, Wv, Wt);
    hipLaunchKernelGGL(proj_kernel, dim3(384), dim3(256), 0, stream,
                       X, Wt, Q16, K16, V16);
    if (ws_size >= ws_need) {
        hipLaunchKernelGGL(attn_split_kernel, dim3(512), dim3(256), 0, stream,
                           Q16, K16, V16, part16, lsumP);
        hipLaunchKernelGGL(merge_kernel, dim3(256), dim3(256), 0, stream,
                           part16, lsumP, Out);
    } else {
        hipLaunchKernelGGL(attn_kernel, dim3(256), dim3(512), 0, stream,
                           Q16, K16, V16, Out);
    }
}

// Round 16
// 102.311 us; speedup vs baseline: 1.7800x; 1.1618x over previous
//
#include <hip/hip_runtime.h>
#include <hip/hip_bf16.h>
#include <math.h>

#define B_  4
#define S_  4096
#define D_  1024
#define KD_ 128
#define NSPL 4            // KV splits
#define NIT  (S_ / NSPL / 32)  // 32 iterations of KBLK=32

typedef __attribute__((ext_vector_type(8))) short short8;
typedef __attribute__((ext_vector_type(4))) float f32x4;
typedef __attribute__((ext_vector_type(16))) float f32x16;
typedef __attribute__((ext_vector_type(4))) unsigned short us4;
typedef __attribute__((ext_vector_type(4))) unsigned int u32x4;

__device__ __forceinline__ unsigned short f2bf(float f) {
    __hip_bfloat16 h = __float2bfloat16(f);
    return *reinterpret_cast<unsigned short*>(&h);
}

__device__ __forceinline__ f32x4 mfma_bf16(short8 a, short8 b, f32x4 c) {
    return __builtin_amdgcn_mfma_f32_16x16x32_bf16(a, b, c, 0, 0, 0);
}

__device__ __forceinline__ f32x16 mfma32_bf16(short8 a, short8 b, f32x16 c) {
    return __builtin_amdgcn_mfma_f32_32x32x16_bf16(a, b, c, 0, 0, 0);
}

__device__ __forceinline__ unsigned int cvt_pk_bf16(float lo, float hi_) {
    unsigned int r;
    asm("v_cvt_pk_bf16_f32 %0, %1, %2" : "=v"(r) : "v"(lo), "v"(hi_));
    return r;
}

__device__ __forceinline__ void g2l16(const void* g, void* l) {
    __builtin_amdgcn_global_load_lds(
        (const __attribute__((address_space(1))) unsigned int*)g,
        (__attribute__((address_space(3))) unsigned int*)l, 16, 0, 0);
}

// ---------------------------------------------------------------------------
// Convert weights [D,128] fp32 -> Wt [3][128][D] bf16 (transposed).
// Q weight folds in log2(e)/sqrt(128) so softmax can use native exp2.
__global__ void convert_w_kernel(const float* __restrict__ wq,
                                 const float* __restrict__ wk,
                                 const float* __restrict__ wv,
                                 unsigned short* __restrict__ wt) {
    int t = blockIdx.x * 256 + threadIdx.x;       // 0..49151
    int w = t >> 14;
    int r = t & 16383;
    int n = r & 127;
    int k8 = r >> 7;                               // 0..127
    const float* src = (w == 0) ? wq : (w == 1) ? wk : wv;
    float scale = (w == 0) ? 0.12751725551033443f : 1.0f;  // log2e/sqrt(128)
    short8 v;
#pragma unroll
    for (int i = 0; i < 8; ++i)
        v[i] = (short)f2bf(src[(size_t)(k8 * 8 + i) * KD_ + n] * scale);
    *reinterpret_cast<short8*>(&wt[(size_t)w * KD_ * D_ + (size_t)n * D_ + k8 * 8]) = v;
}

// ---------------------------------------------------------------------------
// Projection GEMM: C[16384,128] = X[16384,1024] @ W.  NT form, Wt[128][1024].
// R16: reverted to R13's proven 2-barrier structure (R15's T14 chain was
// latency-bound at 6 waves/CU), but 512 threads = 8 waves (2x4), each wave a
// 64x32 sub-tile -> 12 waves/CU, per-block path halved. Same 384-block grid,
// bid = (m&7) + 8*which + 24*(m>>3): 3 which-blocks of one mtile share an XCD.
__global__ __launch_bounds__(512) void proj_kernel(
        const float* __restrict__ X, const unsigned short* __restrict__ Wt,
        unsigned short* __restrict__ Qo, unsigned short* __restrict__ Ko,
        unsigned short* __restrict__ Vt) {
    const int bid = blockIdx.x;
    const int g = bid / 24;
    const int local = bid - g * 24;
    const int which = local >> 3;
    const int mtile = g * 8 + (local & 7);
    const int m0 = mtile * 128;
    const int tid = threadIdx.x;
    const int lane = tid & 63;
    const int wid = tid >> 6;          // 0..7
    const int wr = wid >> 2, wc = wid & 3;   // 2 x 4 wave grid
    const int l15 = lane & 15, l4 = lane >> 4;

    __shared__ __align__(16) unsigned short Asm[128 * 64];   // 16 KiB
    __shared__ __align__(16) unsigned short Bsm[128 * 64];   // 16 KiB
    __shared__ __align__(16) unsigned short Tsm[128 * 128];  // 32 KiB

    const unsigned short* W = Wt + (size_t)which * KD_ * D_;

    f32x4 acc[4][2];
#pragma unroll
    for (int r = 0; r < 4; ++r)
#pragma unroll
        for (int c = 0; c < 2; ++c) acc[r][c] = (f32x4)0.0f;

    for (int k0 = 0; k0 < D_; k0 += 64) {
        // stage A tile 128x64 (fp32 -> bf16): 2048 float4 over 512 threads
#pragma unroll
        for (int i = 0; i < 4; ++i) {
            int f = tid + i * 512;
            int row = f >> 4, c4 = f & 15;
            float4 xv = *reinterpret_cast<const float4*>(
                &X[(size_t)(m0 + row) * D_ + k0 + c4 * 4]);
            us4 h;
            h.x = f2bf(xv.x); h.y = f2bf(xv.y); h.z = f2bf(xv.z); h.w = f2bf(xv.w);
            *reinterpret_cast<us4*>(&Asm[row * 64 + c4 * 4]) = h;
        }
        // stage B tile 128x64 (bf16): 1024 short8 over 512 threads
#pragma unroll
        for (int i = 0; i < 2; ++i) {
            int gg = tid + i * 512;
            int n = gg >> 3, c8 = gg & 7;
            *reinterpret_cast<short8*>(&Bsm[n * 64 + c8 * 8]) =
                *reinterpret_cast<const short8*>(&W[(size_t)n * D_ + k0 + c8 * 8]);
        }
        __syncthreads();

        short8 a[4][2], b[2][2];
#pragma unroll
        for (int rt = 0; rt < 4; ++rt)
#pragma unroll
            for (int kc = 0; kc < 2; ++kc)
                a[rt][kc] = *reinterpret_cast<const short8*>(
                    &Asm[(wr * 64 + rt * 16 + l15) * 64 + kc * 32 + l4 * 8]);
#pragma unroll
        for (int ct = 0; ct < 2; ++ct)
#pragma unroll
            for (int kc = 0; kc < 2; ++kc)
                b[ct][kc] = *reinterpret_cast<const short8*>(
                    &Bsm[(wc * 32 + ct * 16 + l15) * 64 + kc * 32 + l4 * 8]);
        __builtin_amdgcn_s_setprio(1);
#pragma unroll
        for (int kc = 0; kc < 2; ++kc)
#pragma unroll
            for (int rt = 0; rt < 4; ++rt)
#pragma unroll
                for (int ct = 0; ct < 2; ++ct)
                    acc[rt][ct] = mfma_bf16(a[rt][kc], b[ct][kc], acc[rt][ct]);
        __builtin_amdgcn_s_setprio(0);
        __syncthreads();
    }

    if (which < 2) {
        unsigned short* O = (which == 0) ? Qo : Ko;
#pragma unroll
        for (int rt = 0; rt < 4; ++rt)
#pragma unroll
            for (int ct = 0; ct < 2; ++ct)
#pragma unroll
                for (int j = 0; j < 4; ++j) {
                    int row = m0 + wr * 64 + rt * 16 + l4 * 4 + j;
                    int col = wc * 32 + ct * 16 + l15;
                    O[(size_t)row * KD_ + col] = f2bf(acc[rt][ct][j]);
                }
    } else {
        // transpose through LDS, then coalesced store to Vt[b][128][4096]
#pragma unroll
        for (int rt = 0; rt < 4; ++rt)
#pragma unroll
            for (int ct = 0; ct < 2; ++ct)
#pragma unroll
                for (int j = 0; j < 4; ++j) {
                    int row = wr * 64 + rt * 16 + l4 * 4 + j;  // s-local
                    int col = wc * 32 + ct * 16 + l15;          // n
                    Tsm[col * 128 + row] = f2bf(acc[rt][ct][j]);
                }
        __syncthreads();
        int bb = m0 >> 12;
        int s0 = m0 & 4095;
#pragma unroll
        for (int i = 0; i < 4; ++i) {
            int gg = tid + i * 512;        // 16B groups over 2048
            int n = gg >> 4, s8 = gg & 15;
            *reinterpret_cast<short8*>(
                &Vt[(size_t)bb * KD_ * S_ + (size_t)n * S_ + s0 + s8 * 8]) =
                *reinterpret_cast<short8*>(&Tsm[n * 128 + s8 * 8]);
        }
    }
}

// ---------------------------------------------------------------------------
// R16 flash attention = R13 (split-KV x4, 4-deep ring + counted vmcnt,
// separate merge) + 4-bit K swizzle (R14-verified: conflicts 4.19M -> 2.09M).
__global__ __launch_bounds__(256, 2) void attn_split_kernel(
        const unsigned short* __restrict__ Q,
        const unsigned short* __restrict__ Kb,
        const unsigned short* __restrict__ Vt,
        unsigned short* __restrict__ part16, float* __restrict__ lsumP) {
    const int bid = blockIdx.x;       // 0..511
    const int b  = bid & 3;           // xcd = bid%8 -> one batch per XCD (L2)
    const int s  = (bid >> 2) & 3;    // KV split
    const int qt = bid >> 4;          // 0..31 (128-row q tiles)
    const int tid = threadIdx.x;
    const int lane = tid & 63;
    const int wid = tid >> 6;         // wave 0..3
    const int q0 = qt * 128;
    const int l31 = lane & 31;
    const int hi  = lane >> 5;        // 0,1

    __shared__ __align__(16) unsigned short Ksm[4][32 * 128];  // 32 KiB
    __shared__ __align__(16) unsigned short Vsm[4][128 * 32];  // 32 KiB

    // Q fragments: lane holds Q[q = q0+wid*32+l31][k = kc*16 + hi*8 .. +7]
    short8 aq[8];
    {
        const unsigned short* qrow =
            Q + ((size_t)(b * S_ + q0 + wid * 32 + l31)) * KD_;
#pragma unroll
        for (int kc = 0; kc < 8; ++kc)
            aq[kc] = *reinterpret_cast<const short8*>(&qrow[kc * 16 + hi * 8]);
    }

    f32x16 o[4];
#pragma unroll
    for (int dt = 0; dt < 4; ++dt) o[dt] = (f32x16)0.0f;
    float lsA = 0.0f, lsB = 0.0f;

    const unsigned short* Kbase = Kb + (size_t)b * S_ * KD_;
    const unsigned short* Vbase = Vt + (size_t)b * KD_ * S_;

    // stage K[32][128] + V[128][32] global tile kt into ring slot; 4 waves
    // split the granules: exactly 4 g2l16 per wave (2 K + 2 V).
    // K swizzle is 4-bit (c ^ (row&15)) -> reader 2-way conflict (free).
    auto STAGE = [&](int buf, int kt) {
#pragma unroll
        for (int i = 0; i < 2; ++i) {
            int d = i * 256 + wid * 64 + lane;         // K granule 0..511
            int row = d >> 4, c = d & 15;              // 16 granules / 128-row
            g2l16(&Kbase[(size_t)(kt * 32 + row) * KD_ + ((c ^ (row & 15)) * 8)],
                  &Ksm[buf][(i * 256 + wid * 64) * 8]);
        }
#pragma unroll
        for (int i = 0; i < 2; ++i) {
            int d = i * 256 + wid * 64 + lane;         // V granule 0..511
            int row = d >> 2, c = d & 3;               // 4 granules / 32-row
            g2l16(&Vbase[(size_t)row * S_ + kt * 32 + ((c ^ ((row >> 1) & 3)) * 8)],
                  &Vsm[buf][(i * 256 + wid * 64) * 8]);
        }
    };

    const int base = s * NIT;
    STAGE(0, base + 0);
    STAGE(1, base + 1);

    for (int it = 0; it < NIT; ++it) {
        if (it + 2 < NIT) {
            STAGE((it + 2) & 3, base + it + 2);        // 12 outstanding
            asm volatile("s_waitcnt vmcnt(8)" ::: "memory");   // drain tile it
        } else if (it + 1 < NIT) {
            asm volatile("s_waitcnt vmcnt(4)" ::: "memory");
        } else {
            asm volatile("s_waitcnt vmcnt(0)" ::: "memory");
        }
        __builtin_amdgcn_s_barrier();   // publish tile it block-wide

        const unsigned short* ksm = &Ksm[it & 3][0];
        const unsigned short* vsm = &Vsm[it & 3][0];

        // S^T = K Q^T : one 32x32 tile per wave, q = l31 lane-local.
        f32x16 sf = (f32x16)0.0f;
        __builtin_amdgcn_s_setprio(1);
#pragma unroll
        for (int kc = 0; kc < 8; ++kc) {
            short8 bk = *reinterpret_cast<const short8*>(
                &ksm[l31 * 128 + (((kc * 2 + hi) ^ (l31 & 15)) * 8)]);
            sf = mfma32_bf16(bk, aq[kc], sf);
        }
        __builtin_amdgcn_s_setprio(0);

        // p = exp2(s_pre), per-lane row sum (2 chains); pack P to bf16 PV
        // A-frags in-register: kv(r) = (r&3)+8*(r>>2)+4*hi.
        float p[16];
#pragma unroll
        for (int r = 0; r < 16; ++r) {
            p[r] = exp2f(sf[r]);
            if (r & 1) lsB += p[r]; else lsA += p[r];
        }

        short8 pa[2];
#pragma unroll
        for (int c = 0; c < 2; ++c) {
            u32x4 wv;
#pragma unroll
            for (int e = 0; e < 2; ++e) {
                unsigned int X = cvt_pk_bf16(p[8 * c + 2 * e], p[8 * c + 2 * e + 1]);
                unsigned int Y = cvt_pk_bf16(p[8 * c + 4 + 2 * e], p[8 * c + 4 + 2 * e + 1]);
                unsigned int Ss = hi ? X : Y;
                unsigned int T = __shfl_xor(Ss, 32);
                wv[e]     = hi ? T : X;
                wv[2 + e] = hi ? Y : T;
            }
            pa[c] = __builtin_bit_cast(short8, wv);
        }

        // O += P V : A = P (q=l31 rows, kv-chunk c), B = Vt rows (d cols).
        __builtin_amdgcn_s_setprio(1);
#pragma unroll
        for (int c = 0; c < 2; ++c)
#pragma unroll
            for (int dt = 0; dt < 4; ++dt) {
                int row = dt * 32 + l31;
                short8 bv = *reinterpret_cast<const short8*>(
                    &vsm[row * 32 + (((c * 2 + hi) ^ ((row >> 1) & 3)) * 8)]);
                o[dt] = mfma32_bf16(pa[c], bv, o[dt]);
            }
        __builtin_amdgcn_s_setprio(0);
        // no trailing barrier: ring depth 4 + barrier chain provides WAR
    }

    float lsum = lsA + lsB;
    lsum += __shfl_xor(lsum, 32);     // other kv half lives in lane^32

    // write bf16 partial tile (128x128) + f32 sums (disjoint per block)
    const int tile = (qt << 2) | b;   // 0..127
    unsigned short* Po = part16 + ((size_t)tile * NSPL + s) * 16384;
#pragma unroll
    for (int r = 0; r < 16; ++r) {
        int row = wid * 32 + (r & 3) + 8 * (r >> 2) + 4 * hi;
#pragma unroll
        for (int dt = 0; dt < 4; ++dt)
            Po[row * 128 + dt * 32 + l31] = f2bf(o[dt][r]);
    }
    if (hi == 0)
        lsumP[((size_t)tile * NSPL + s) * 128 + wid * 32 + l31] = lsum;
}

// ---------------------------------------------------------------------------
// Merge 4 bf16 KV-split partials: out = sum(part_s) / sum(lsum_s).
// 256 blocks, each merges a 64-row half of one 128x128 tile.
__global__ __launch_bounds__(256) void merge_kernel(
        const unsigned short* __restrict__ part16,
        const float* __restrict__ lsumP, float* __restrict__ Out) {
    const int th = blockIdx.x;        // 0..255
    const int tile = th >> 1;         // 0..127 = qt*4 + b
    const int half = th & 1;
    const int b = tile & 3, qt = tile >> 2;
    const int r0 = half * 64;
    const int tid = threadIdx.x;
    __shared__ float inv[64];
    if (tid < 64) {
        const float* lp = lsumP + (size_t)tile * (NSPL * 128) + r0;
        float t = 0.0f;
#pragma unroll
        for (int s = 0; s < NSPL; ++s) t += lp[s * 128 + tid];
        inv[tid] = 1.0f / t;
    }
    __syncthreads();
    const unsigned short* p = part16 + (size_t)tile * NSPL * 16384 + r0 * 128;
    float* Ob = Out + ((size_t)b * S_ + qt * 128 + r0) * KD_;
#pragma unroll
    for (int i = 0; i < 4; ++i) {
        int g = tid + i * 256;        // short8 group, 0..1023 (64x128 half)
        int row = g >> 4;
        float acc8[8] = {0, 0, 0, 0, 0, 0, 0, 0};
#pragma unroll
        for (int s = 0; s < NSPL; ++s) {
            short8 v = *reinterpret_cast<const short8*>(&p[s * 16384 + g * 8]);
#pragma unroll
            for (int j = 0; j < 8; ++j) {
                unsigned int u = ((unsigned int)(unsigned short)v[j]) << 16;
                acc8[j] += __uint_as_float(u);
            }
        }
        float iv = inv[row];
        float4 r0v, r1v;
        r0v.x = acc8[0] * iv; r0v.y = acc8[1] * iv;
        r0v.z = acc8[2] * iv; r0v.w = acc8[3] * iv;
        r1v.x = acc8[4] * iv; r1v.y = acc8[5] * iv;
        r1v.z = acc8[6] * iv; r1v.w = acc8[7] * iv;
        *reinterpret_cast<float4*>(&Ob[g * 8]) = r0v;
        *reinterpret_cast<float4*>(&Ob[g * 8 + 4]) = r1v;
    }
}

// ---------------------------------------------------------------------------
// Fallback (R8-style, exp2f, 4-bit K swizzle): single-block-per-qtile,
// in-block merge. Used if ws_size is too small for the split partials.
__global__ __launch_bounds__(512, 2) void attn_kernel(
        const unsigned short* __restrict__ Q,
        const unsigned short* __restrict__ Kb,
        const unsigned short* __restrict__ Vt,
        float* __restrict__ Out) {
    const int bid = blockIdx.x;
    const int b  = bid & 3;
    const int qt = bid >> 2;
    const int tid = threadIdx.x;
    const int lane = tid & 63;
    const int wid = tid >> 6;
    const int grp = wid >> 1;
    const int wg  = wid & 1;
    const int q0 = qt * 64;
    const int l31 = lane & 31;
    const int hi  = lane >> 5;

    __shared__ __align__(16) unsigned char lds_raw[131072];
    unsigned short* KsmA = (unsigned short*)lds_raw;
    unsigned short* VsmA = (unsigned short*)(lds_raw + 65536);

    short8 aq[8];
    {
        const unsigned short* qrow =
            Q + ((size_t)(b * S_ + q0 + wg * 32 + l31)) * KD_;
#pragma unroll
        for (int kc = 0; kc < 8; ++kc)
            aq[kc] = *reinterpret_cast<const short8*>(&qrow[kc * 16 + hi * 8]);
    }

    f32x16 o[4];
#pragma unroll
    for (int dt = 0; dt < 4; ++dt) o[dt] = (f32x16)0.0f;
    float lsum = 0.0f;

    const unsigned short* Kbase = Kb + (size_t)b * S_ * KD_;
    const unsigned short* Vbase = Vt + (size_t)b * KD_ * S_;

    unsigned short* Kgrp = KsmA + grp * 2 * 4096;
    unsigned short* Vgrp = VsmA + grp * 2 * 4096;

    auto STAGE = [&](int buf, int kt) {
#pragma unroll
        for (int i = 0; i < 4; ++i) {
            int d = i * 128 + wg * 64 + lane;
            int row = d >> 4, c = d & 15;
            g2l16(&Kbase[(size_t)(kt * 32 + row) * KD_ + ((c ^ (row & 15)) * 8)],
                  &Kgrp[(buf * 512 + i * 128 + wg * 64) * 8]);
        }
#pragma unroll
        for (int i = 0; i < 4; ++i) {
            int d = i * 128 + wg * 64 + lane;
            int row = d >> 2, c = d & 3;
            g2l16(&Vbase[(size_t)row * S_ + kt * 32 + ((c ^ ((row >> 1) & 3)) * 8)],
                  &Vgrp[(buf * 512 + i * 128 + wg * 64) * 8]);
        }
    };

    int cur = 0;
    STAGE(0, grp);
    __syncthreads();

    for (int it = 0; it < 32; ++it) {
        if (it < 31) STAGE(cur ^ 1, (it + 1) * 4 + grp);

        const unsigned short* ksm = Kgrp + cur * 4096;
        const unsigned short* vsm = Vgrp + cur * 4096;

        f32x16 sf = (f32x16)0.0f;
        __builtin_amdgcn_s_setprio(1);
#pragma unroll
        for (int kc = 0; kc < 8; ++kc) {
            short8 bk = *reinterpret_cast<const short8*>(
                &ksm[l31 * 128 + (((kc * 2 + hi) ^ (l31 & 15)) * 8)]);
            sf = mfma32_bf16(bk, aq[kc], sf);
        }
        __builtin_amdgcn_s_setprio(0);

        float p[16];
#pragma unroll
        for (int r = 0; r < 16; ++r) {
            p[r] = exp2f(sf[r]);
            lsum += p[r];
        }

        short8 pa[2];
#pragma unroll
        for (int c = 0; c < 2; ++c) {
            u32x4 wv;
#pragma unroll
            for (int e = 0; e < 2; ++e) {
                unsigned int X = cvt_pk_bf16(p[8 * c + 2 * e], p[8 * c + 2 * e + 1]);
                unsigned int Y = cvt_pk_bf16(p[8 * c + 4 + 2 * e], p[8 * c + 4 + 2 * e + 1]);
                unsigned int Ss = hi ? X : Y;
                unsigned int T = __shfl_xor(Ss, 32);
                wv[e]     = hi ? T : X;
                wv[2 + e] = hi ? Y : T;
            }
            pa[c] = __builtin_bit_cast(short8, wv);
        }

        __builtin_amdgcn_s_setprio(1);
#pragma unroll
        for (int c = 0; c < 2; ++c)
#pragma unroll
            for (int dt = 0; dt < 4; ++dt) {
                int row = dt * 32 + l31;
                short8 bv = *reinterpret_cast<const short8*>(
                    &vsm[row * 32 + (((c * 2 + hi) ^ ((row >> 1) & 3)) * 8)]);
                o[dt] = mfma32_bf16(pa[c], bv, o[dt]);
            }
        __builtin_amdgcn_s_setprio(0);

        __syncthreads();
        cur ^= 1;
    }

    lsum += __shfl_xor(lsum, 32);

    float* scratch = (float*)lds_raw;
    float* lsumS   = (float*)(lds_raw + 98304);
    __syncthreads();
    if (grp >= 1) {
        int base = (grp - 1) * 8192;
#pragma unroll
        for (int dt = 0; dt < 4; ++dt)
#pragma unroll
            for (int r = 0; r < 16; ++r) {
                int row = wg * 32 + (r & 3) + 8 * (r >> 2) + 4 * hi;
                scratch[base + row * 128 + dt * 32 + l31] = o[dt][r];
            }
    }
    if (hi == 0) lsumS[grp * 64 + wg * 32 + l31] = lsum;
    __syncthreads();
    if (grp == 0) {
        float* Ob = Out + (size_t)b * S_ * KD_;
#pragma unroll
        for (int r = 0; r < 16; ++r) {
            int row = wg * 32 + (r & 3) + 8 * (r >> 2) + 4 * hi;
            float inv = 1.0f / (lsumS[row] + lsumS[64 + row] +
                                lsumS[128 + row] + lsumS[192 + row]);
#pragma unroll
            for (int dt = 0; dt < 4; ++dt) {
                int col = dt * 32 + l31;
                int idx = row * 128 + col;
                float v = o[dt][r] + scratch[idx] + scratch[8192 + idx] +
                          scratch[16384 + idx];
                Ob[(size_t)(q0 + row) * KD_ + col] = v * inv;
            }
        }
    }
}

// ---------------------------------------------------------------------------
extern "C" void kernel_launch(void* const* d_in, const int* in_sizes, int n_in,
                              void* d_out, int out_size, void* d_ws, size_t ws_size,
                              hipStream_t stream) {
    const float* X  = (const float*)d_in[0];
    const float* Wq = (const float*)d_in[1];
    const float* Wk = (const float*)d_in[2];
    const float* Wv = (const float*)d_in[3];
    float* Out = (float*)d_out;

    unsigned short* Wt  = (unsigned short*)d_ws;                    // 768 KiB
    unsigned short* Q16 = (unsigned short*)((char*)d_ws + 786432);  // 4 MiB
    unsigned short* K16 = Q16 + (size_t)16384 * 128;                // 4 MiB
    unsigned short* V16 = K16 + (size_t)16384 * 128;                // 4 MiB (Vt)
    unsigned short* part16 = (unsigned short*)((char*)d_ws + 13369344); // 16 MiB
    float* lsumP = (float*)((char*)d_ws + 13369344 + 16777216);     // 256 KiB
    const size_t ws_need = 13369344 + 16777216 + 262144;            // ~30.4 MB

    hipLaunchKernelGGL(convert_w_kernel, dim3(192), dim3(256), 0, stream,
                       Wq, Wk, Wv, Wt);
    hipLaunchKernelGGL(proj_kernel, dim3(384), dim3(512), 0, stream,
                       X, Wt, Q16, K16, V16);
    if (ws_size >= ws_need) {
        hipLaunchKernelGGL(attn_split_kernel, dim3(512), dim3(256), 0, stream,
                           Q16, K16, V16, part16, lsumP);
        hipLaunchKernelGGL(merge_kernel, dim3(256), dim3(256), 0, stream,
                           part16, lsumP, Out);
    } else {
        hipLaunchKernelGGL(attn_kernel, dim3(256), dim3(512), 0, stream,
                           Q16, K16, V16, Out);
    }
}

// Round 17
// 94.225 us; speedup vs baseline: 1.9328x; 1.0858x over previous
//
#include <hip/hip_runtime.h>
#include <hip/hip_bf16.h>
#include <math.h>

#define B_  4
#define S_  4096
#define D_  1024
#define KD_ 128
#define NSPL 4            // KV splits
#define NIT  (S_ / NSPL / 32)  // 32 iterations of KBLK=32

typedef __attribute__((ext_vector_type(8))) short short8;
typedef __attribute__((ext_vector_type(4))) float f32x4;
typedef __attribute__((ext_vector_type(16))) float f32x16;
typedef __attribute__((ext_vector_type(4))) unsigned short us4;
typedef __attribute__((ext_vector_type(4))) unsigned int u32x4;

__device__ __forceinline__ unsigned short f2bf(float f) {
    __hip_bfloat16 h = __float2bfloat16(f);
    return *reinterpret_cast<unsigned short*>(&h);
}

__device__ __forceinline__ f32x4 mfma_bf16(short8 a, short8 b, f32x4 c) {
    return __builtin_amdgcn_mfma_f32_16x16x32_bf16(a, b, c, 0, 0, 0);
}

__device__ __forceinline__ f32x16 mfma32_bf16(short8 a, short8 b, f32x16 c) {
    return __builtin_amdgcn_mfma_f32_32x32x16_bf16(a, b, c, 0, 0, 0);
}

__device__ __forceinline__ unsigned int cvt_pk_bf16(float lo, float hi_) {
    unsigned int r;
    asm("v_cvt_pk_bf16_f32 %0, %1, %2" : "=v"(r) : "v"(lo), "v"(hi_));
    return r;
}

__device__ __forceinline__ void g2l16(const void* g, void* l) {
    __builtin_amdgcn_global_load_lds(
        (const __attribute__((address_space(1))) unsigned int*)g,
        (__attribute__((address_space(3))) unsigned int*)l, 16, 0, 0);
}

// ---------------------------------------------------------------------------
// Convert weights [D,128] fp32 -> Wt [3][128][D] bf16 (transposed).
// Q weight folds in log2(e)/sqrt(128) so softmax can use native exp2.
__global__ void convert_w_kernel(const float* __restrict__ wq,
                                 const float* __restrict__ wk,
                                 const float* __restrict__ wv,
                                 unsigned short* __restrict__ wt) {
    int t = blockIdx.x * 256 + threadIdx.x;       // 0..49151
    int w = t >> 14;
    int r = t & 16383;
    int n = r & 127;
    int k8 = r >> 7;                               // 0..127
    const float* src = (w == 0) ? wq : (w == 1) ? wk : wv;
    float scale = (w == 0) ? 0.12751725551033443f : 1.0f;  // log2e/sqrt(128)
    short8 v;
#pragma unroll
    for (int i = 0; i < 8; ++i)
        v[i] = (short)f2bf(src[(size_t)(k8 * 8 + i) * KD_ + n] * scale);
    *reinterpret_cast<short8*>(&wt[(size_t)w * KD_ * D_ + (size_t)n * D_ + k8 * 8]) = v;
}

// ---------------------------------------------------------------------------
// Projection GEMM: C[16384,128] = X[16384,1024] @ W.  NT form, Wt[128][1024].
// R17: R16 structure + T2 XOR-swizzle on Asm/Bsm (16B granule g -> g^(row&7)).
// R16's proj showed 7.57M bank-conflict cycles: 128B-row tiles give 16-way
// conflicts on every fragment ds_read_b128; swizzle makes them 2-way (free).
// bid = (m&7) + 8*which + 24*(m>>3): 3 which-blocks of one mtile share an XCD.
__global__ __launch_bounds__(512) void proj_kernel(
        const float* __restrict__ X, const unsigned short* __restrict__ Wt,
        unsigned short* __restrict__ Qo, unsigned short* __restrict__ Ko,
        unsigned short* __restrict__ Vt) {
    const int bid = blockIdx.x;
    const int g = bid / 24;
    const int local = bid - g * 24;
    const int which = local >> 3;
    const int mtile = g * 8 + (local & 7);
    const int m0 = mtile * 128;
    const int tid = threadIdx.x;
    const int lane = tid & 63;
    const int wid = tid >> 6;          // 0..7
    const int wr = wid >> 2, wc = wid & 3;   // 2 x 4 wave grid
    const int l15 = lane & 15, l4 = lane >> 4;

    __shared__ __align__(16) unsigned short Asm[128 * 64];   // 16 KiB
    __shared__ __align__(16) unsigned short Bsm[128 * 64];   // 16 KiB
    __shared__ __align__(16) unsigned short Tsm[128 * 128];  // 32 KiB

    const unsigned short* W = Wt + (size_t)which * KD_ * D_;

    f32x4 acc[4][2];
#pragma unroll
    for (int r = 0; r < 4; ++r)
#pragma unroll
        for (int c = 0; c < 2; ++c) acc[r][c] = (f32x4)0.0f;

    for (int k0 = 0; k0 < D_; k0 += 64) {
        // stage A tile 128x64 (fp32 -> bf16), swizzled 16B granules
#pragma unroll
        for (int i = 0; i < 4; ++i) {
            int f = tid + i * 512;
            int row = f >> 4, c4 = f & 15;        // c4 = 8B granule (16/row)
            float4 xv = *reinterpret_cast<const float4*>(
                &X[(size_t)(m0 + row) * D_ + k0 + c4 * 4]);
            us4 h;
            h.x = f2bf(xv.x); h.y = f2bf(xv.y); h.z = f2bf(xv.z); h.w = f2bf(xv.w);
            int gw = c4 >> 1, half = c4 & 1;      // 16B granule + half
            *reinterpret_cast<us4*>(
                &Asm[row * 64 + ((gw ^ (row & 7)) * 8) + half * 4]) = h;
        }
        // stage B tile 128x64 (bf16), swizzled 16B granules
#pragma unroll
        for (int i = 0; i < 2; ++i) {
            int gg = tid + i * 512;
            int n = gg >> 3, c8 = gg & 7;         // c8 = 16B granule (8/row)
            *reinterpret_cast<short8*>(&Bsm[n * 64 + ((c8 ^ (n & 7)) * 8)]) =
                *reinterpret_cast<const short8*>(&W[(size_t)n * D_ + k0 + c8 * 8]);
        }
        __syncthreads();

        short8 a[4][2], b[2][2];
#pragma unroll
        for (int rt = 0; rt < 4; ++rt)
#pragma unroll
            for (int kc = 0; kc < 2; ++kc) {
                int row = wr * 64 + rt * 16 + l15;
                int gr = kc * 4 + l4;
                a[rt][kc] = *reinterpret_cast<const short8*>(
                    &Asm[row * 64 + ((gr ^ (row & 7)) * 8)]);
            }
#pragma unroll
        for (int ct = 0; ct < 2; ++ct)
#pragma unroll
            for (int kc = 0; kc < 2; ++kc) {
                int row = wc * 32 + ct * 16 + l15;
                int gr = kc * 4 + l4;
                b[ct][kc] = *reinterpret_cast<const short8*>(
                    &Bsm[row * 64 + ((gr ^ (row & 7)) * 8)]);
            }
        __builtin_amdgcn_s_setprio(1);
#pragma unroll
        for (int kc = 0; kc < 2; ++kc)
#pragma unroll
            for (int rt = 0; rt < 4; ++rt)
#pragma unroll
                for (int ct = 0; ct < 2; ++ct)
                    acc[rt][ct] = mfma_bf16(a[rt][kc], b[ct][kc], acc[rt][ct]);
        __builtin_amdgcn_s_setprio(0);
        __syncthreads();
    }

    if (which < 2) {
        unsigned short* O = (which == 0) ? Qo : Ko;
#pragma unroll
        for (int rt = 0; rt < 4; ++rt)
#pragma unroll
            for (int ct = 0; ct < 2; ++ct)
#pragma unroll
                for (int j = 0; j < 4; ++j) {
                    int row = m0 + wr * 64 + rt * 16 + l4 * 4 + j;
                    int col = wc * 32 + ct * 16 + l15;
                    O[(size_t)row * KD_ + col] = f2bf(acc[rt][ct][j]);
                }
    } else {
        // transpose through LDS, then coalesced store to Vt[b][128][4096]
#pragma unroll
        for (int rt = 0; rt < 4; ++rt)
#pragma unroll
            for (int ct = 0; ct < 2; ++ct)
#pragma unroll
                for (int j = 0; j < 4; ++j) {
                    int row = wr * 64 + rt * 16 + l4 * 4 + j;  // s-local
                    int col = wc * 32 + ct * 16 + l15;          // n
                    Tsm[col * 128 + row] = f2bf(acc[rt][ct][j]);
                }
        __syncthreads();
        int bb = m0 >> 12;
        int s0 = m0 & 4095;
#pragma unroll
        for (int i = 0; i < 4; ++i) {
            int gg = tid + i * 512;        // 16B groups over 2048
            int n = gg >> 4, s8 = gg & 15;
            *reinterpret_cast<short8*>(
                &Vt[(size_t)bb * KD_ * S_ + (size_t)n * S_ + s0 + s8 * 8]) =
                *reinterpret_cast<short8*>(&Tsm[n * 128 + s8 * 8]);
        }
    }
}

// ---------------------------------------------------------------------------
// R17 flash attention = R13 (split-KV x4, 4-deep ring + counted vmcnt,
// separate merge) + 4-bit K swizzle (R14-verified: conflicts 4.19M -> 2.09M).
__global__ __launch_bounds__(256, 2) void attn_split_kernel(
        const unsigned short* __restrict__ Q,
        const unsigned short* __restrict__ Kb,
        const unsigned short* __restrict__ Vt,
        unsigned short* __restrict__ part16, float* __restrict__ lsumP) {
    const int bid = blockIdx.x;       // 0..511
    const int b  = bid & 3;           // xcd = bid%8 -> one batch per XCD (L2)
    const int s  = (bid >> 2) & 3;    // KV split
    const int qt = bid >> 4;          // 0..31 (128-row q tiles)
    const int tid = threadIdx.x;
    const int lane = tid & 63;
    const int wid = tid >> 6;         // wave 0..3
    const int q0 = qt * 128;
    const int l31 = lane & 31;
    const int hi  = lane >> 5;        // 0,1

    __shared__ __align__(16) unsigned short Ksm[4][32 * 128];  // 32 KiB
    __shared__ __align__(16) unsigned short Vsm[4][128 * 32];  // 32 KiB

    // Q fragments: lane holds Q[q = q0+wid*32+l31][k = kc*16 + hi*8 .. +7]
    short8 aq[8];
    {
        const unsigned short* qrow =
            Q + ((size_t)(b * S_ + q0 + wid * 32 + l31)) * KD_;
#pragma unroll
        for (int kc = 0; kc < 8; ++kc)
            aq[kc] = *reinterpret_cast<const short8*>(&qrow[kc * 16 + hi * 8]);
    }

    f32x16 o[4];
#pragma unroll
    for (int dt = 0; dt < 4; ++dt) o[dt] = (f32x16)0.0f;
    float lsA = 0.0f, lsB = 0.0f;

    const unsigned short* Kbase = Kb + (size_t)b * S_ * KD_;
    const unsigned short* Vbase = Vt + (size_t)b * KD_ * S_;

    // stage K[32][128] + V[128][32] global tile kt into ring slot; 4 waves
    // split the granules: exactly 4 g2l16 per wave (2 K + 2 V).
    // K swizzle is 4-bit (c ^ (row&15)) -> reader 2-way conflict (free).
    auto STAGE = [&](int buf, int kt) {
#pragma unroll
        for (int i = 0; i < 2; ++i) {
            int d = i * 256 + wid * 64 + lane;         // K granule 0..511
            int row = d >> 4, c = d & 15;              // 16 granules / 128-row
            g2l16(&Kbase[(size_t)(kt * 32 + row) * KD_ + ((c ^ (row & 15)) * 8)],
                  &Ksm[buf][(i * 256 + wid * 64) * 8]);
        }
#pragma unroll
        for (int i = 0; i < 2; ++i) {
            int d = i * 256 + wid * 64 + lane;         // V granule 0..511
            int row = d >> 2, c = d & 3;               // 4 granules / 32-row
            g2l16(&Vbase[(size_t)row * S_ + kt * 32 + ((c ^ ((row >> 1) & 3)) * 8)],
                  &Vsm[buf][(i * 256 + wid * 64) * 8]);
        }
    };

    const int base = s * NIT;
    STAGE(0, base + 0);
    STAGE(1, base + 1);

    for (int it = 0; it < NIT; ++it) {
        if (it + 2 < NIT) {
            STAGE((it + 2) & 3, base + it + 2);        // 12 outstanding
            asm volatile("s_waitcnt vmcnt(8)" ::: "memory");   // drain tile it
        } else if (it + 1 < NIT) {
            asm volatile("s_waitcnt vmcnt(4)" ::: "memory");
        } else {
            asm volatile("s_waitcnt vmcnt(0)" ::: "memory");
        }
        __builtin_amdgcn_s_barrier();   // publish tile it block-wide

        const unsigned short* ksm = &Ksm[it & 3][0];
        const unsigned short* vsm = &Vsm[it & 3][0];

        // S^T = K Q^T : one 32x32 tile per wave, q = l31 lane-local.
        f32x16 sf = (f32x16)0.0f;
        __builtin_amdgcn_s_setprio(1);
#pragma unroll
        for (int kc = 0; kc < 8; ++kc) {
            short8 bk = *reinterpret_cast<const short8*>(
                &ksm[l31 * 128 + (((kc * 2 + hi) ^ (l31 & 15)) * 8)]);
            sf = mfma32_bf16(bk, aq[kc], sf);
        }
        __builtin_amdgcn_s_setprio(0);

        // p = exp2(s_pre), per-lane row sum (2 chains); pack P to bf16 PV
        // A-frags in-register: kv(r) = (r&3)+8*(r>>2)+4*hi.
        float p[16];
#pragma unroll
        for (int r = 0; r < 16; ++r) {
            p[r] = exp2f(sf[r]);
            if (r & 1) lsB += p[r]; else lsA += p[r];
        }

        short8 pa[2];
#pragma unroll
        for (int c = 0; c < 2; ++c) {
            u32x4 wv;
#pragma unroll
            for (int e = 0; e < 2; ++e) {
                unsigned int X = cvt_pk_bf16(p[8 * c + 2 * e], p[8 * c + 2 * e + 1]);
                unsigned int Y = cvt_pk_bf16(p[8 * c + 4 + 2 * e], p[8 * c + 4 + 2 * e + 1]);
                unsigned int Ss = hi ? X : Y;
                unsigned int T = __shfl_xor(Ss, 32);
                wv[e]     = hi ? T : X;
                wv[2 + e] = hi ? Y : T;
            }
            pa[c] = __builtin_bit_cast(short8, wv);
        }

        // O += P V : A = P (q=l31 rows, kv-chunk c), B = Vt rows (d cols).
        __builtin_amdgcn_s_setprio(1);
#pragma unroll
        for (int c = 0; c < 2; ++c)
#pragma unroll
            for (int dt = 0; dt < 4; ++dt) {
                int row = dt * 32 + l31;
                short8 bv = *reinterpret_cast<const short8*>(
                    &vsm[row * 32 + (((c * 2 + hi) ^ ((row >> 1) & 3)) * 8)]);
                o[dt] = mfma32_bf16(pa[c], bv, o[dt]);
            }
        __builtin_amdgcn_s_setprio(0);
        // no trailing barrier: ring depth 4 + barrier chain provides WAR
    }

    float lsum = lsA + lsB;
    lsum += __shfl_xor(lsum, 32);     // other kv half lives in lane^32

    // write bf16 partial tile (128x128) + f32 sums (disjoint per block)
    const int tile = (qt << 2) | b;   // 0..127
    unsigned short* Po = part16 + ((size_t)tile * NSPL + s) * 16384;
#pragma unroll
    for (int r = 0; r < 16; ++r) {
        int row = wid * 32 + (r & 3) + 8 * (r >> 2) + 4 * hi;
#pragma unroll
        for (int dt = 0; dt < 4; ++dt)
            Po[row * 128 + dt * 32 + l31] = f2bf(o[dt][r]);
    }
    if (hi == 0)
        lsumP[((size_t)tile * NSPL + s) * 128 + wid * 32 + l31] = lsum;
}

// ---------------------------------------------------------------------------
// Merge 4 bf16 KV-split partials: out = sum(part_s) / sum(lsum_s).
// 256 blocks, each merges a 64-row half of one 128x128 tile.
__global__ __launch_bounds__(256) void merge_kernel(
        const unsigned short* __restrict__ part16,
        const float* __restrict__ lsumP, float* __restrict__ Out) {
    const int th = blockIdx.x;        // 0..255
    const int tile = th >> 1;         // 0..127 = qt*4 + b
    const int half = th & 1;
    const int b = tile & 3, qt = tile >> 2;
    const int r0 = half * 64;
    const int tid = threadIdx.x;
    __shared__ float inv[64];
    if (tid < 64) {
        const float* lp = lsumP + (size_t)tile * (NSPL * 128) + r0;
        float t = 0.0f;
#pragma unroll
        for (int s = 0; s < NSPL; ++s) t += lp[s * 128 + tid];
        inv[tid] = 1.0f / t;
    }
    __syncthreads();
    const unsigned short* p = part16 + (size_t)tile * NSPL * 16384 + r0 * 128;
    float* Ob = Out + ((size_t)b * S_ + qt * 128 + r0) * KD_;
#pragma unroll
    for (int i = 0; i < 4; ++i) {
        int g = tid + i * 256;        // short8 group, 0..1023 (64x128 half)
        int row = g >> 4;
        float acc8[8] = {0, 0, 0, 0, 0, 0, 0, 0};
#pragma unroll
        for (int s = 0; s < NSPL; ++s) {
            short8 v = *reinterpret_cast<const short8*>(&p[s * 16384 + g * 8]);
#pragma unroll
            for (int j = 0; j < 8; ++j) {
                unsigned int u = ((unsigned int)(unsigned short)v[j]) << 16;
                acc8[j] += __uint_as_float(u);
            }
        }
        float iv = inv[row];
        float4 r0v, r1v;
        r0v.x = acc8[0] * iv; r0v.y = acc8[1] * iv;
        r0v.z = acc8[2] * iv; r0v.w = acc8[3] * iv;
        r1v.x = acc8[4] * iv; r1v.y = acc8[5] * iv;
        r1v.z = acc8[6] * iv; r1v.w = acc8[7] * iv;
        *reinterpret_cast<float4*>(&Ob[g * 8]) = r0v;
        *reinterpret_cast<float4*>(&Ob[g * 8 + 4]) = r1v;
    }
}

// ---------------------------------------------------------------------------
// Fallback (R8-style, exp2f, 4-bit K swizzle): single-block-per-qtile,
// in-block merge. Used if ws_size is too small for the split partials.
__global__ __launch_bounds__(512, 2) void attn_kernel(
        const unsigned short* __restrict__ Q,
        const unsigned short* __restrict__ Kb,
        const unsigned short* __restrict__ Vt,
        float* __restrict__ Out) {
    const int bid = blockIdx.x;
    const int b  = bid & 3;
    const int qt = bid >> 2;
    const int tid = threadIdx.x;
    const int lane = tid & 63;
    const int wid = tid >> 6;
    const int grp = wid >> 1;
    const int wg  = wid & 1;
    const int q0 = qt * 64;
    const int l31 = lane & 31;
    const int hi  = lane >> 5;

    __shared__ __align__(16) unsigned char lds_raw[131072];
    unsigned short* KsmA = (unsigned short*)lds_raw;
    unsigned short* VsmA = (unsigned short*)(lds_raw + 65536);

    short8 aq[8];
    {
        const unsigned short* qrow =
            Q + ((size_t)(b * S_ + q0 + wg * 32 + l31)) * KD_;
#pragma unroll
        for (int kc = 0; kc < 8; ++kc)
            aq[kc] = *reinterpret_cast<const short8*>(&qrow[kc * 16 + hi * 8]);
    }

    f32x16 o[4];
#pragma unroll
    for (int dt = 0; dt < 4; ++dt) o[dt] = (f32x16)0.0f;
    float lsum = 0.0f;

    const unsigned short* Kbase = Kb + (size_t)b * S_ * KD_;
    const unsigned short* Vbase = Vt + (size_t)b * KD_ * S_;

    unsigned short* Kgrp = KsmA + grp * 2 * 4096;
    unsigned short* Vgrp = VsmA + grp * 2 * 4096;

    auto STAGE = [&](int buf, int kt) {
#pragma unroll
        for (int i = 0; i < 4; ++i) {
            int d = i * 128 + wg * 64 + lane;
            int row = d >> 4, c = d & 15;
            g2l16(&Kbase[(size_t)(kt * 32 + row) * KD_ + ((c ^ (row & 15)) * 8)],
                  &Kgrp[(buf * 512 + i * 128 + wg * 64) * 8]);
        }
#pragma unroll
        for (int i = 0; i < 4; ++i) {
            int d = i * 128 + wg * 64 + lane;
            int row = d >> 2, c = d & 3;
            g2l16(&Vbase[(size_t)row * S_ + kt * 32 + ((c ^ ((row >> 1) & 3)) * 8)],
                  &Vgrp[(buf * 512 + i * 128 + wg * 64) * 8]);
        }
    };

    int cur = 0;
    STAGE(0, grp);
    __syncthreads();

    for (int it = 0; it < 32; ++it) {
        if (it < 31) STAGE(cur ^ 1, (it + 1) * 4 + grp);

        const unsigned short* ksm = Kgrp + cur * 4096;
        const unsigned short* vsm = Vgrp + cur * 4096;

        f32x16 sf = (f32x16)0.0f;
        __builtin_amdgcn_s_setprio(1);
#pragma unroll
        for (int kc = 0; kc < 8; ++kc) {
            short8 bk = *reinterpret_cast<const short8*>(
                &ksm[l31 * 128 + (((kc * 2 + hi) ^ (l31 & 15)) * 8)]);
            sf = mfma32_bf16(bk, aq[kc], sf);
        }
        __builtin_amdgcn_s_setprio(0);

        float p[16];
#pragma unroll
        for (int r = 0; r < 16; ++r) {
            p[r] = exp2f(sf[r]);
            lsum += p[r];
        }

        short8 pa[2];
#pragma unroll
        for (int c = 0; c < 2; ++c) {
            u32x4 wv;
#pragma unroll
            for (int e = 0; e < 2; ++e) {
                unsigned int X = cvt_pk_bf16(p[8 * c + 2 * e], p[8 * c + 2 * e + 1]);
                unsigned int Y = cvt_pk_bf16(p[8 * c + 4 + 2 * e], p[8 * c + 4 + 2 * e + 1]);
                unsigned int Ss = hi ? X : Y;
                unsigned int T = __shfl_xor(Ss, 32);
                wv[e]     = hi ? T : X;
                wv[2 + e] = hi ? Y : T;
            }
            pa[c] = __builtin_bit_cast(short8, wv);
        }

        __builtin_amdgcn_s_setprio(1);
#pragma unroll
        for (int c = 0; c < 2; ++c)
#pragma unroll
            for (int dt = 0; dt < 4; ++dt) {
                int row = dt * 32 + l31;
                short8 bv = *reinterpret_cast<const short8*>(
                    &vsm[row * 32 + (((c * 2 + hi) ^ ((row >> 1) & 3)) * 8)]);
                o[dt] = mfma32_bf16(pa[c], bv, o[dt]);
            }
        __builtin_amdgcn_s_setprio(0);

        __syncthreads();
        cur ^= 1;
    }

    lsum += __shfl_xor(lsum, 32);

    float* scratch = (float*)lds_raw;
    float* lsumS   = (float*)(lds_raw + 98304);
    __syncthreads();
    if (grp >= 1) {
        int base = (grp - 1) * 8192;
#pragma unroll
        for (int dt = 0; dt < 4; ++dt)
#pragma unroll
            for (int r = 0; r < 16; ++r) {
                int row = wg * 32 + (r & 3) + 8 * (r >> 2) + 4 * hi;
                scratch[base + row * 128 + dt * 32 + l31] = o[dt][r];
            }
    }
    if (hi == 0) lsumS[grp * 64 + wg * 32 + l31] = lsum;
    __syncthreads();
    if (grp == 0) {
        float* Ob = Out + (size_t)b * S_ * KD_;
#pragma unroll
        for (int r = 0; r < 16; ++r) {
            int row = wg * 32 + (r & 3) + 8 * (r >> 2) + 4 * hi;
            float inv = 1.0f / (lsumS[row] + lsumS[64 + row] +
                                lsumS[128 + row] + lsumS[192 + row]);
#pragma unroll
            for (int dt = 0; dt < 4; ++dt) {
                int col = dt * 32 + l31;
                int idx = row * 128 + col;
                float v = o[dt][r] + scratch[idx] + scratch[8192 + idx] +
                          scratch[16384 + idx];
                Ob[(size_t)(q0 + row) * KD_ + col] = v * inv;
            }
        }
    }
}

// ---------------------------------------------------------------------------
extern "C" void kernel_launch(void* const* d_in, const int* in_sizes, int n_in,
                              void* d_out, int out_size, void* d_ws, size_t ws_size,
                              hipStream_t stream) {
    const float* X  = (const float*)d_in[0];
    const float* Wq = (const float*)d_in[1];
    const float* Wk = (const float*)d_in[2];
    const float* Wv = (const float*)d_in[3];
    float* Out = (float*)d_out;

    unsigned short* Wt  = (unsigned short*)d_ws;                    // 768 KiB
    unsigned short* Q16 = (unsigned short*)((char*)d_ws + 786432);  // 4 MiB
    unsigned short* K16 = Q16 + (size_t)16384 * 128;                // 4 MiB
    unsigned short* V16 = K16 + (size_t)16384 * 128;                // 4 MiB (Vt)
    unsigned short* part16 = (unsigned short*)((char*)d_ws + 13369344); // 16 MiB
    float* lsumP = (float*)((char*)d_ws + 13369344 + 16777216);     // 256 KiB
    const size_t ws_need = 13369344 + 16777216 + 262144;            // ~30.4 MB

    hipLaunchKernelGGL(convert_w_kernel, dim3(192), dim3(256), 0, stream,
                       Wq, Wk, Wv, Wt);
    hipLaunchKernelGGL(proj_kernel, dim3(384), dim3(512), 0, stream,
                       X, Wt, Q16, K16, V16);
    if (ws_size >= ws_need) {
        hipLaunchKernelGGL(attn_split_kernel, dim3(512), dim3(256), 0, stream,
                           Q16, K16, V16, part16, lsumP);
        hipLaunchKernelGGL(merge_kernel, dim3(256), dim3(256), 0, stream,
                           part16, lsumP, Out);
    } else {
        hipLaunchKernelGGL(attn_kernel, dim3(256), dim3(512), 0, stream,
                           Q16, K16, V16, Out);
    }
}

// Round 18
// 92.762 us; speedup vs baseline: 1.9633x; 1.0158x over previous
//
#include <hip/hip_runtime.h>
#include <hip/hip_bf16.h>
#include <math.h>

#define B_  4
#define S_  4096
#define D_  1024
#define KD_ 128
#define NSPL 4              // KV splits
#define NIT64 (S_ / NSPL / 64)  // 16 iterations of KBLK=64

typedef __attribute__((ext_vector_type(8))) short short8;
typedef __attribute__((ext_vector_type(4))) float f32x4;
typedef __attribute__((ext_vector_type(16))) float f32x16;
typedef __attribute__((ext_vector_type(4))) unsigned short us4;
typedef __attribute__((ext_vector_type(4))) unsigned int u32x4;

__device__ __forceinline__ unsigned short f2bf(float f) {
    __hip_bfloat16 h = __float2bfloat16(f);
    return *reinterpret_cast<unsigned short*>(&h);
}

__device__ __forceinline__ f32x4 mfma_bf16(short8 a, short8 b, f32x4 c) {
    return __builtin_amdgcn_mfma_f32_16x16x32_bf16(a, b, c, 0, 0, 0);
}

__device__ __forceinline__ f32x16 mfma32_bf16(short8 a, short8 b, f32x16 c) {
    return __builtin_amdgcn_mfma_f32_32x32x16_bf16(a, b, c, 0, 0, 0);
}

__device__ __forceinline__ unsigned int cvt_pk_bf16(float lo, float hi_) {
    unsigned int r;
    asm("v_cvt_pk_bf16_f32 %0, %1, %2" : "=v"(r) : "v"(lo), "v"(hi_));
    return r;
}

__device__ __forceinline__ void g2l16(const void* g, void* l) {
    __builtin_amdgcn_global_load_lds(
        (const __attribute__((address_space(1))) unsigned int*)g,
        (__attribute__((address_space(3))) unsigned int*)l, 16, 0, 0);
}

// ---------------------------------------------------------------------------
// Convert weights [D,128] fp32 -> Wt [3][128][D] bf16 (transposed).
// Q weight folds in log2(e)/sqrt(128) so softmax can use native exp2.
__global__ void convert_w_kernel(const float* __restrict__ wq,
                                 const float* __restrict__ wk,
                                 const float* __restrict__ wv,
                                 unsigned short* __restrict__ wt) {
    int t = blockIdx.x * 256 + threadIdx.x;       // 0..49151
    int w = t >> 14;
    int r = t & 16383;
    int n = r & 127;
    int k8 = r >> 7;                               // 0..127
    const float* src = (w == 0) ? wq : (w == 1) ? wk : wv;
    float scale = (w == 0) ? 0.12751725551033443f : 1.0f;  // log2e/sqrt(128)
    short8 v;
#pragma unroll
    for (int i = 0; i < 8; ++i)
        v[i] = (short)f2bf(src[(size_t)(k8 * 8 + i) * KD_ + n] * scale);
    *reinterpret_cast<short8*>(&wt[(size_t)w * KD_ * D_ + (size_t)n * D_ + k8 * 8]) = v;
}

// ---------------------------------------------------------------------------
// Projection GEMM (R17, unchanged): 512 threads, T2-swizzled Asm/Bsm.
__global__ __launch_bounds__(512) void proj_kernel(
        const float* __restrict__ X, const unsigned short* __restrict__ Wt,
        unsigned short* __restrict__ Qo, unsigned short* __restrict__ Ko,
        unsigned short* __restrict__ Vt) {
    const int bid = blockIdx.x;
    const int g = bid / 24;
    const int local = bid - g * 24;
    const int which = local >> 3;
    const int mtile = g * 8 + (local & 7);
    const int m0 = mtile * 128;
    const int tid = threadIdx.x;
    const int lane = tid & 63;
    const int wid = tid >> 6;          // 0..7
    const int wr = wid >> 2, wc = wid & 3;   // 2 x 4 wave grid
    const int l15 = lane & 15, l4 = lane >> 4;

    __shared__ __align__(16) unsigned short Asm[128 * 64];   // 16 KiB
    __shared__ __align__(16) unsigned short Bsm[128 * 64];   // 16 KiB
    __shared__ __align__(16) unsigned short Tsm[128 * 128];  // 32 KiB

    const unsigned short* W = Wt + (size_t)which * KD_ * D_;

    f32x4 acc[4][2];
#pragma unroll
    for (int r = 0; r < 4; ++r)
#pragma unroll
        for (int c = 0; c < 2; ++c) acc[r][c] = (f32x4)0.0f;

    for (int k0 = 0; k0 < D_; k0 += 64) {
#pragma unroll
        for (int i = 0; i < 4; ++i) {
            int f = tid + i * 512;
            int row = f >> 4, c4 = f & 15;
            float4 xv = *reinterpret_cast<const float4*>(
                &X[(size_t)(m0 + row) * D_ + k0 + c4 * 4]);
            us4 h;
            h.x = f2bf(xv.x); h.y = f2bf(xv.y); h.z = f2bf(xv.z); h.w = f2bf(xv.w);
            int gw = c4 >> 1, half = c4 & 1;
            *reinterpret_cast<us4*>(
                &Asm[row * 64 + ((gw ^ (row & 7)) * 8) + half * 4]) = h;
        }
#pragma unroll
        for (int i = 0; i < 2; ++i) {
            int gg = tid + i * 512;
            int n = gg >> 3, c8 = gg & 7;
            *reinterpret_cast<short8*>(&Bsm[n * 64 + ((c8 ^ (n & 7)) * 8)]) =
                *reinterpret_cast<const short8*>(&W[(size_t)n * D_ + k0 + c8 * 8]);
        }
        __syncthreads();

        short8 a[4][2], b[2][2];
#pragma unroll
        for (int rt = 0; rt < 4; ++rt)
#pragma unroll
            for (int kc = 0; kc < 2; ++kc) {
                int row = wr * 64 + rt * 16 + l15;
                int gr = kc * 4 + l4;
                a[rt][kc] = *reinterpret_cast<const short8*>(
                    &Asm[row * 64 + ((gr ^ (row & 7)) * 8)]);
            }
#pragma unroll
        for (int ct = 0; ct < 2; ++ct)
#pragma unroll
            for (int kc = 0; kc < 2; ++kc) {
                int row = wc * 32 + ct * 16 + l15;
                int gr = kc * 4 + l4;
                b[ct][kc] = *reinterpret_cast<const short8*>(
                    &Bsm[row * 64 + ((gr ^ (row & 7)) * 8)]);
            }
        __builtin_amdgcn_s_setprio(1);
#pragma unroll
        for (int kc = 0; kc < 2; ++kc)
#pragma unroll
            for (int rt = 0; rt < 4; ++rt)
#pragma unroll
                for (int ct = 0; ct < 2; ++ct)
                    acc[rt][ct] = mfma_bf16(a[rt][kc], b[ct][kc], acc[rt][ct]);
        __builtin_amdgcn_s_setprio(0);
        __syncthreads();
    }

    if (which < 2) {
        unsigned short* O = (which == 0) ? Qo : Ko;
#pragma unroll
        for (int rt = 0; rt < 4; ++rt)
#pragma unroll
            for (int ct = 0; ct < 2; ++ct)
#pragma unroll
                for (int j = 0; j < 4; ++j) {
                    int row = m0 + wr * 64 + rt * 16 + l4 * 4 + j;
                    int col = wc * 32 + ct * 16 + l15;
                    O[(size_t)row * KD_ + col] = f2bf(acc[rt][ct][j]);
                }
    } else {
#pragma unroll
        for (int rt = 0; rt < 4; ++rt)
#pragma unroll
            for (int ct = 0; ct < 2; ++ct)
#pragma unroll
                for (int j = 0; j < 4; ++j) {
                    int row = wr * 64 + rt * 16 + l4 * 4 + j;  // s-local
                    int col = wc * 32 + ct * 16 + l15;          // n
                    Tsm[col * 128 + row] = f2bf(acc[rt][ct][j]);
                }
        __syncthreads();
        int bb = m0 >> 12;
        int s0 = m0 & 4095;
#pragma unroll
        for (int i = 0; i < 4; ++i) {
            int gg = tid + i * 512;
            int n = gg >> 4, s8 = gg & 15;
            *reinterpret_cast<short8*>(
                &Vt[(size_t)bb * KD_ * S_ + (size_t)n * S_ + s0 + s8 * 8]) =
                *reinterpret_cast<short8*>(&Tsm[n * 128 + s8 * 8]);
        }
    }
}

// ---------------------------------------------------------------------------
// R18 flash attention: split-KV x4, KBLK=64, ring-2 (32KB K + 32KB V slots).
// Per iter: vmcnt(0) [drains loads issued one FULL iteration ago - no stall]
// -> s_barrier -> STAGE(it+1) [after barrier => WAR-safe vs tile it-1]
// -> compute 2 kv-halves. Halves barrier/vmcnt/loop count vs R13's KBLK=32
// (R17 analysis: ~1600cy/iter residual sync overhead paid 32x).
__global__ __launch_bounds__(256, 2) void attn_split_kernel(
        const unsigned short* __restrict__ Q,
        const unsigned short* __restrict__ Kb,
        const unsigned short* __restrict__ Vt,
        unsigned short* __restrict__ part16, float* __restrict__ lsumP) {
    const int bid = blockIdx.x;       // 0..511
    const int b  = bid & 3;           // xcd = bid%8 -> one batch per XCD (L2)
    const int s  = (bid >> 2) & 3;    // KV split
    const int qt = bid >> 4;          // 0..31 (128-row q tiles)
    const int tid = threadIdx.x;
    const int lane = tid & 63;
    const int wid = tid >> 6;         // wave 0..3
    const int q0 = qt * 128;
    const int l31 = lane & 31;
    const int hi  = lane >> 5;        // 0,1

    __shared__ __align__(16) unsigned short Ksm[2][64 * 128];  // 32 KiB
    __shared__ __align__(16) unsigned short Vsm[2][128 * 64];  // 32 KiB

    // Q fragments: lane holds Q[q = q0+wid*32+l31][k = kc*16 + hi*8 .. +7]
    short8 aq[8];
    {
        const unsigned short* qrow =
            Q + ((size_t)(b * S_ + q0 + wid * 32 + l31)) * KD_;
#pragma unroll
        for (int kc = 0; kc < 8; ++kc)
            aq[kc] = *reinterpret_cast<const short8*>(&qrow[kc * 16 + hi * 8]);
    }

    f32x16 o[4];
#pragma unroll
    for (int dt = 0; dt < 4; ++dt) o[dt] = (f32x16)0.0f;
    float lsA = 0.0f, lsB = 0.0f;

    const unsigned short* Kbase = Kb + (size_t)b * S_ * KD_;
    const unsigned short* Vbase = Vt + (size_t)b * KD_ * S_;

    // stage K[64][128] + V[128][64] tile kt (64 kv rows) into ring slot.
    // 4 waves split 2048 granules: 8 g2l16 per wave (4 K + 4 V).
    // K: 16 granules/row, swizzle c^(row&15); V: 8/row, swizzle c^(row&7).
    auto STAGE = [&](int buf, int kt) {
#pragma unroll
        for (int i = 0; i < 4; ++i) {
            int d = i * 256 + wid * 64 + lane;         // K granule 0..1023
            int row = d >> 4, c = d & 15;
            g2l16(&Kbase[(size_t)(kt * 64 + row) * KD_ + ((c ^ (row & 15)) * 8)],
                  &Ksm[buf][(i * 256 + wid * 64) * 8]);
        }
#pragma unroll
        for (int i = 0; i < 4; ++i) {
            int d = i * 256 + wid * 64 + lane;         // V granule 0..1023
            int row = d >> 3, c = d & 7;
            g2l16(&Vbase[(size_t)row * S_ + kt * 64 + ((c ^ (row & 7)) * 8)],
                  &Vsm[buf][(i * 256 + wid * 64) * 8]);
        }
    };

    const int base = s * NIT64;
    STAGE(0, base);

    for (int it = 0; it < NIT64; ++it) {
        asm volatile("s_waitcnt vmcnt(0)" ::: "memory");  // drain tile it
        __builtin_amdgcn_s_barrier();                      // publish block-wide
        if (it + 1 < NIT64) STAGE((it + 1) & 1, base + it + 1);

        const unsigned short* ksm = &Ksm[it & 1][0];
        const unsigned short* vsm = &Vsm[it & 1][0];

#pragma unroll
        for (int h = 0; h < 2; ++h) {
            // S^T = K Q^T for kv-half h: rows kv = h*32 + l31.
            f32x16 sf = (f32x16)0.0f;
            __builtin_amdgcn_s_setprio(1);
#pragma unroll
            for (int kc = 0; kc < 8; ++kc) {
                int row = h * 32 + l31;
                short8 bk = *reinterpret_cast<const short8*>(
                    &ksm[row * 128 + (((kc * 2 + hi) ^ (l31 & 15)) * 8)]);
                sf = mfma32_bf16(bk, aq[kc], sf);
            }
            __builtin_amdgcn_s_setprio(0);

            // p = exp2(s_pre), per-lane row sums; pack P to bf16 A-frags:
            // kv(r) = h*32 + (r&3)+8*(r>>2)+4*hi.
            float p[16];
#pragma unroll
            for (int r = 0; r < 16; ++r) {
                p[r] = exp2f(sf[r]);
                if (r & 1) lsB += p[r]; else lsA += p[r];
            }

            short8 pa[2];
#pragma unroll
            for (int c = 0; c < 2; ++c) {
                u32x4 wv;
#pragma unroll
                for (int e = 0; e < 2; ++e) {
                    unsigned int X = cvt_pk_bf16(p[8 * c + 2 * e], p[8 * c + 2 * e + 1]);
                    unsigned int Y = cvt_pk_bf16(p[8 * c + 4 + 2 * e], p[8 * c + 4 + 2 * e + 1]);
                    unsigned int Ss = hi ? X : Y;
                    unsigned int T = __shfl_xor(Ss, 32);
                    wv[e]     = hi ? T : X;
                    wv[2 + e] = hi ? Y : T;
                }
                pa[c] = __builtin_bit_cast(short8, wv);
            }

            // O += P V : kv chunk (h*2+c), B granule = chunk*2 + hi.
            __builtin_amdgcn_s_setprio(1);
#pragma unroll
            for (int c = 0; c < 2; ++c)
#pragma unroll
                for (int dt = 0; dt < 4; ++dt) {
                    int row = dt * 32 + l31;
                    int gr = (h * 2 + c) * 2 + hi;
                    short8 bv = *reinterpret_cast<const short8*>(
                        &vsm[row * 64 + ((gr ^ (row & 7)) * 8)]);
                    o[dt] = mfma32_bf16(pa[c], bv, o[dt]);
                }
            __builtin_amdgcn_s_setprio(0);
        }
        // no trailing barrier: ring-2 + stage-after-barrier provides WAR
    }

    float lsum = lsA + lsB;
    lsum += __shfl_xor(lsum, 32);     // other kv half lives in lane^32

    // write bf16 partial tile (128x128) + f32 sums (disjoint per block)
    const int tile = (qt << 2) | b;   // 0..127
    unsigned short* Po = part16 + ((size_t)tile * NSPL + s) * 16384;
#pragma unroll
    for (int r = 0; r < 16; ++r) {
        int row = wid * 32 + (r & 3) + 8 * (r >> 2) + 4 * hi;
#pragma unroll
        for (int dt = 0; dt < 4; ++dt)
            Po[row * 128 + dt * 32 + l31] = f2bf(o[dt][r]);
    }
    if (hi == 0)
        lsumP[((size_t)tile * NSPL + s) * 128 + wid * 32 + l31] = lsum;
}

// ---------------------------------------------------------------------------
// Merge 4 bf16 KV-split partials: out = sum(part_s) / sum(lsum_s).
// 256 blocks, each merges a 64-row half of one 128x128 tile.
__global__ __launch_bounds__(256) void merge_kernel(
        const unsigned short* __restrict__ part16,
        const float* __restrict__ lsumP, float* __restrict__ Out) {
    const int th = blockIdx.x;        // 0..255
    const int tile = th >> 1;         // 0..127 = qt*4 + b
    const int half = th & 1;
    const int b = tile & 3, qt = tile >> 2;
    const int r0 = half * 64;
    const int tid = threadIdx.x;
    __shared__ float inv[64];
    if (tid < 64) {
        const float* lp = lsumP + (size_t)tile * (NSPL * 128) + r0;
        float t = 0.0f;
#pragma unroll
        for (int s = 0; s < NSPL; ++s) t += lp[s * 128 + tid];
        inv[tid] = 1.0f / t;
    }
    __syncthreads();
    const unsigned short* p = part16 + (size_t)tile * NSPL * 16384 + r0 * 128;
    float* Ob = Out + ((size_t)b * S_ + qt * 128 + r0) * KD_;
#pragma unroll
    for (int i = 0; i < 4; ++i) {
        int g = tid + i * 256;        // short8 group, 0..1023 (64x128 half)
        int row = g >> 4;
        float acc8[8] = {0, 0, 0, 0, 0, 0, 0, 0};
#pragma unroll
        for (int s = 0; s < NSPL; ++s) {
            short8 v = *reinterpret_cast<const short8*>(&p[s * 16384 + g * 8]);
#pragma unroll
            for (int j = 0; j < 8; ++j) {
                unsigned int u = ((unsigned int)(unsigned short)v[j]) << 16;
                acc8[j] += __uint_as_float(u);
            }
        }
        float iv = inv[row];
        float4 r0v, r1v;
        r0v.x = acc8[0] * iv; r0v.y = acc8[1] * iv;
        r0v.z = acc8[2] * iv; r0v.w = acc8[3] * iv;
        r1v.x = acc8[4] * iv; r1v.y = acc8[5] * iv;
        r1v.z = acc8[6] * iv; r1v.w = acc8[7] * iv;
        *reinterpret_cast<float4*>(&Ob[g * 8]) = r0v;
        *reinterpret_cast<float4*>(&Ob[g * 8 + 4]) = r1v;
    }
}

// ---------------------------------------------------------------------------
// Fallback (R8-style, exp2f, 4-bit K swizzle): single-block-per-qtile,
// in-block merge. Used if ws_size is too small for the split partials.
__global__ __launch_bounds__(512, 2) void attn_kernel(
        const unsigned short* __restrict__ Q,
        const unsigned short* __restrict__ Kb,
        const unsigned short* __restrict__ Vt,
        float* __restrict__ Out) {
    const int bid = blockIdx.x;
    const int b  = bid & 3;
    const int qt = bid >> 2;
    const int tid = threadIdx.x;
    const int lane = tid & 63;
    const int wid = tid >> 6;
    const int grp = wid >> 1;
    const int wg  = wid & 1;
    const int q0 = qt * 64;
    const int l31 = lane & 31;
    const int hi  = lane >> 5;

    __shared__ __align__(16) unsigned char lds_raw[131072];
    unsigned short* KsmA = (unsigned short*)lds_raw;
    unsigned short* VsmA = (unsigned short*)(lds_raw + 65536);

    short8 aq[8];
    {
        const unsigned short* qrow =
            Q + ((size_t)(b * S_ + q0 + wg * 32 + l31)) * KD_;
#pragma unroll
        for (int kc = 0; kc < 8; ++kc)
            aq[kc] = *reinterpret_cast<const short8*>(&qrow[kc * 16 + hi * 8]);
    }

    f32x16 o[4];
#pragma unroll
    for (int dt = 0; dt < 4; ++dt) o[dt] = (f32x16)0.0f;
    float lsum = 0.0f;

    const unsigned short* Kbase = Kb + (size_t)b * S_ * KD_;
    const unsigned short* Vbase = Vt + (size_t)b * KD_ * S_;

    unsigned short* Kgrp = KsmA + grp * 2 * 4096;
    unsigned short* Vgrp = VsmA + grp * 2 * 4096;

    auto STAGE = [&](int buf, int kt) {
#pragma unroll
        for (int i = 0; i < 4; ++i) {
            int d = i * 128 + wg * 64 + lane;
            int row = d >> 4, c = d & 15;
            g2l16(&Kbase[(size_t)(kt * 32 + row) * KD_ + ((c ^ (row & 15)) * 8)],
                  &Kgrp[(buf * 512 + i * 128 + wg * 64) * 8]);
        }
#pragma unroll
        for (int i = 0; i < 4; ++i) {
            int d = i * 128 + wg * 64 + lane;
            int row = d >> 2, c = d & 3;
            g2l16(&Vbase[(size_t)row * S_ + kt * 32 + ((c ^ ((row >> 1) & 3)) * 8)],
                  &Vgrp[(buf * 512 + i * 128 + wg * 64) * 8]);
        }
    };

    int cur = 0;
    STAGE(0, grp);
    __syncthreads();

    for (int it = 0; it < 32; ++it) {
        if (it < 31) STAGE(cur ^ 1, (it + 1) * 4 + grp);

        const unsigned short* ksm = Kgrp + cur * 4096;
        const unsigned short* vsm = Vgrp + cur * 4096;

        f32x16 sf = (f32x16)0.0f;
        __builtin_amdgcn_s_setprio(1);
#pragma unroll
        for (int kc = 0; kc < 8; ++kc) {
            short8 bk = *reinterpret_cast<const short8*>(
                &ksm[l31 * 128 + (((kc * 2 + hi) ^ (l31 & 15)) * 8)]);
            sf = mfma32_bf16(bk, aq[kc], sf);
        }
        __builtin_amdgcn_s_setprio(0);

        float p[16];
#pragma unroll
        for (int r = 0; r < 16; ++r) {
            p[r] = exp2f(sf[r]);
            lsum += p[r];
        }

        short8 pa[2];
#pragma unroll
        for (int c = 0; c < 2; ++c) {
            u32x4 wv;
#pragma unroll
            for (int e = 0; e < 2; ++e) {
                unsigned int X = cvt_pk_bf16(p[8 * c + 2 * e], p[8 * c + 2 * e + 1]);
                unsigned int Y = cvt_pk_bf16(p[8 * c + 4 + 2 * e], p[8 * c + 4 + 2 * e + 1]);
                unsigned int Ss = hi ? X : Y;
                unsigned int T = __shfl_xor(Ss, 32);
                wv[e]     = hi ? T : X;
                wv[2 + e] = hi ? Y : T;
            }
            pa[c] = __builtin_bit_cast(short8, wv);
        }

        __builtin_amdgcn_s_setprio(1);
#pragma unroll
        for (int c = 0; c < 2; ++c)
#pragma unroll
            for (int dt = 0; dt < 4; ++dt) {
                int row = dt * 32 + l31;
                short8 bv = *reinterpret_cast<const short8*>(
                    &vsm[row * 32 + (((c * 2 + hi) ^ ((row >> 1) & 3)) * 8)]);
                o[dt] = mfma32_bf16(pa[c], bv, o[dt]);
            }
        __builtin_amdgcn_s_setprio(0);

        __syncthreads();
        cur ^= 1;
    }

    lsum += __shfl_xor(lsum, 32);

    float* scratch = (float*)lds_raw;
    float* lsumS   = (float*)(lds_raw + 98304);
    __syncthreads();
    if (grp >= 1) {
        int base = (grp - 1) * 8192;
#pragma unroll
        for (int dt = 0; dt < 4; ++dt)
#pragma unroll
            for (int r = 0; r < 16; ++r) {
                int row = wg * 32 + (r & 3) + 8 * (r >> 2) + 4 * hi;
                scratch[base + row * 128 + dt * 32 + l31] = o[dt][r];
            }
    }
    if (hi == 0) lsumS[grp * 64 + wg * 32 + l31] = lsum;
    __syncthreads();
    if (grp == 0) {
        float* Ob = Out + (size_t)b * S_ * KD_;
#pragma unroll
        for (int r = 0; r < 16; ++r) {
            int row = wg * 32 + (r & 3) + 8 * (r >> 2) + 4 * hi;
            float inv = 1.0f / (lsumS[row] + lsumS[64 + row] +
                                lsumS[128 + row] + lsumS[192 + row]);
#pragma unroll
            for (int dt = 0; dt < 4; ++dt) {
                int col = dt * 32 + l31;
                int idx = row * 128 + col;
                float v = o[dt][r] + scratch[idx] + scratch[8192 + idx] +
                          scratch[16384 + idx];
                Ob[(size_t)(q0 + row) * KD_ + col] = v * inv;
            }
        }
    }
}

// ---------------------------------------------------------------------------
extern "C" void kernel_launch(void* const* d_in, const int* in_sizes, int n_in,
                              void* d_out, int out_size, void* d_ws, size_t ws_size,
                              hipStream_t stream) {
    const float* X  = (const float*)d_in[0];
    const float* Wq = (const float*)d_in[1];
    const float* Wk = (const float*)d_in[2];
    const float* Wv = (const float*)d_in[3];
    float* Out = (float*)d_out;

    unsigned short* Wt  = (unsigned short*)d_ws;                    // 768 KiB
    unsigned short* Q16 = (unsigned short*)((char*)d_ws + 786432);  // 4 MiB
    unsigned short* K16 = Q16 + (size_t)16384 * 128;                // 4 MiB
    unsigned short* V16 = K16 + (size_t)16384 * 128;                // 4 MiB (Vt)
    unsigned short* part16 = (unsigned short*)((char*)d_ws + 13369344); // 16 MiB
    float* lsumP = (float*)((char*)d_ws + 13369344 + 16777216);     // 256 KiB
    const size_t ws_need = 13369344 + 16777216 + 262144;            // ~30.4 MB

    hipLaunchKernelGGL(convert_w_kernel, dim3(192), dim3(256), 0, stream,
                       Wq, Wk, Wv, Wt);
    hipLaunchKernelGGL(proj_kernel, dim3(384), dim3(512), 0, stream,
                       X, Wt, Q16, K16, V16);
    if (ws_size >= ws_need) {
        hipLaunchKernelGGL(attn_split_kernel, dim3(512), dim3(256), 0, stream,
                           Q16, K16, V16, part16, lsumP);
        hipLaunchKernelGGL(merge_kernel, dim3(256), dim3(256), 0, stream,
                           part16, lsumP, Out);
    } else {
        hipLaunchKernelGGL(attn_kernel, dim3(256), dim3(512), 0, stream,
                           Q16, K16, V16, Out);
    }
}